// Round 1
// baseline (4342.614 us; speedup 1.0000x reference)
//
#include <hip/hip_runtime.h>

#define N_NODES 10000
#define N_EDGES 160000
#define CIN 64
#define COUT 128
#define KTOT 125
#define EPS 1e-5f

#define CDIV(a,b) (((a)+(b)-1)/(b))

typedef __attribute__((ext_vector_type(8))) short short8;
typedef __attribute__((ext_vector_type(4))) float floatx4;

static __device__ __forceinline__ unsigned short f2b(float f) {
  union { float f; unsigned u; } v; v.f = f;
  unsigned r = v.u + 0x7FFFu + ((v.u >> 16) & 1u);
  return (unsigned short)(r >> 16);
}

// ---------------- CSR build ----------------
__global__ void count_kernel(const int* __restrict__ dst, int* __restrict__ cnt, int E) {
  int e = blockIdx.x * 256 + threadIdx.x;
  if (e < E) atomicAdd(&cnt[dst[e]], 1);
}

__global__ void scan_kernel(const int* __restrict__ cnt, int* __restrict__ rowptr, int n) {
  __shared__ int buf[256];
  __shared__ int carry;
  if (threadIdx.x == 0) { carry = 0; rowptr[0] = 0; }
  __syncthreads();
  for (int base = 0; base < n; base += 256) {
    int i = base + threadIdx.x;
    int v = (i < n) ? cnt[i] : 0;
    buf[threadIdx.x] = v;
    __syncthreads();
    for (int s = 1; s < 256; s <<= 1) {
      int t = (threadIdx.x >= s) ? buf[threadIdx.x - s] : 0;
      __syncthreads();
      buf[threadIdx.x] += t;
      __syncthreads();
    }
    if (i < n) rowptr[i + 1] = carry + buf[threadIdx.x];
    __syncthreads();
    if (threadIdx.x == 255) carry += buf[255];
    __syncthreads();
  }
}

// per-edge: place into CSR slot, compute 8 spline corners (w, idx)
__global__ void build_sorted(const int* __restrict__ src, const int* __restrict__ dst,
                             const float* __restrict__ attr, const int* __restrict__ rowptr,
                             int* __restrict__ cursor, int* __restrict__ ssrc,
                             float* __restrict__ wts, unsigned char* __restrict__ cidx, int E) {
  int e = blockIdx.x * 256 + threadIdx.x;
  if (e >= E) return;
  int d = dst[e];
  int pos = rowptr[d] + atomicAdd(&cursor[d], 1);
  ssrc[pos] = src[e];
  float v0 = attr[e * 3 + 0] * 4.f;
  float v1 = attr[e * 3 + 1] * 4.f;
  float v2 = attr[e * 3 + 2] * 4.f;
  float b0f = floorf(v0), b1f = floorf(v1), b2f = floorf(v2);
  float f0 = v0 - b0f, f1 = v1 - b1f, f2 = v2 - b2f;
  int i0 = (int)b0f, i1 = (int)b1f, i2 = (int)b2f;
#pragma unroll
  for (int combo = 0; combo < 8; combo++) {
    int bit0 = combo & 1, bit1 = (combo >> 1) & 1, bit2 = (combo >> 2) & 1;
    float w = (bit0 ? f0 : 1.f - f0) * (bit1 ? f1 : 1.f - f1) * (bit2 ? f2 : 1.f - f2);
    int k0 = min(max(i0 + bit0, 0), 4);
    int k1 = min(max(i1 + bit1, 0), 4);
    int k2 = min(max(i2 + bit2, 0), 4);
    cidx[(long)pos * 8 + combo] = (unsigned char)(k0 * 25 + k1 * 5 + k2);
    wts[(long)pos * 8 + combo] = w;
  }
}

// ---------------- converts ----------------
__global__ void f2b_kernel(const float* __restrict__ in, unsigned short* __restrict__ out, long n) {
  long i = (long)blockIdx.x * 256 + threadIdx.x;
  if (i < n) out[i] = f2b(in[i]);
}

// in: fp32 [K][C] row-major  ->  out: bf16 [C][K]
__global__ void transpose_f2b(const float* __restrict__ in, unsigned short* __restrict__ out,
                              int K, int C) {
  long i = (long)blockIdx.x * 256 + threadIdx.x;
  long tot = (long)K * C;
  if (i >= tot) return;
  int k = (int)(i / C), c = (int)(i % C);
  out[(long)c * K + k] = f2b(in[i]);
}

// ---------------- scatter: per-node LDS accumulate -> bf16 acc rows ----------------
__global__ void scatter_kernel(const float* __restrict__ X, const int* __restrict__ rowptr,
                               const int* __restrict__ ssrc, const float* __restrict__ wts,
                               const unsigned char* __restrict__ cidx,
                               unsigned short* __restrict__ accb, int chunk0, int cin) {
  int node = chunk0 + blockIdx.x;
  extern __shared__ float accs[];
  int tot = KTOT * cin;
  for (int i = threadIdx.x; i < tot; i += 256) accs[i] = 0.f;
  __syncthreads();
  int b0 = rowptr[node], b1 = rowptr[node + 1];
  int lane_c = threadIdx.x & (cin - 1);
  int sub = threadIdx.x / cin;
  int epb = 256 / cin;
  for (int e = b0 + sub; e < b1; e += epb) {
    float xv = X[(long)ssrc[e] * cin + lane_c];
#pragma unroll
    for (int c = 0; c < 8; c++) {
      float w = wts[(long)e * 8 + c];
      int k = cidx[(long)e * 8 + c];
      atomicAdd(&accs[k * cin + lane_c], w * xv);
    }
  }
  __syncthreads();
  unsigned short* dstp = accb + (long)blockIdx.x * tot;
  for (int i = threadIdx.x; i < tot; i += 256) dstp[i] = f2b(accs[i]);
}

// ---------------- bf16 MFMA GEMM: C[M,128] = A[M,K] * Bt[128,K]^T ----------------
__global__ __launch_bounds__(256) void gemm_bf16(const unsigned short* __restrict__ A,
                                                 const unsigned short* __restrict__ Bt,
                                                 float* __restrict__ C, int M, int K) {
  int w = threadIdx.x >> 6, l = threadIdx.x & 63;
  int q = l >> 4, m = l & 15;
  int arow = blockIdx.x * 64 + w * 16 + m;
  long ar = (arow < M) ? arow : 0;
  const unsigned short* Ap = A + ar * (long)K + q * 8;
  floatx4 acc[8];
#pragma unroll
  for (int t = 0; t < 8; t++) acc[t] = (floatx4){0.f, 0.f, 0.f, 0.f};
  for (int k0 = 0; k0 < K; k0 += 32) {
    short8 a = *(const short8*)(Ap + k0);
#pragma unroll
    for (int t = 0; t < 8; t++) {
      const unsigned short* Bp = Bt + (long)(t * 16 + m) * K + q * 8 + k0;
      short8 b = *(const short8*)Bp;
      acc[t] = __builtin_amdgcn_mfma_f32_16x16x32_bf16(a, b, acc[t], 0, 0, 0);
    }
  }
  int orow0 = blockIdx.x * 64 + w * 16 + q * 4;
#pragma unroll
  for (int t = 0; t < 8; t++) {
#pragma unroll
    for (int r = 0; r < 4; r++) {
      int rr = orow0 + r;
      if (rr < M) C[(long)rr * COUT + t * 16 + m] = acc[t][r];
    }
  }
}

// ---------------- epilogues ----------------
__global__ void finalize_kernel(const float* __restrict__ msg, const float* __restrict__ root,
                                const float* __restrict__ bias, const int* __restrict__ deg,
                                float* __restrict__ out, int n, int divide) {
  long i = (long)blockIdx.x * 256 + threadIdx.x;
  if (i >= (long)n * COUT) return;
  int r = (int)(i >> 7), c = (int)(i & 127);
  float mv = msg[i];
  if (divide) { float d = (float)deg[r]; mv = mv / fmaxf(d, 1.0f); }
  out[i] = mv + root[i] + bias[c];
}

__global__ void bn_stats(const float* __restrict__ h, float* __restrict__ stats, int n) {
  int c = threadIdx.x & 127;
  int half = threadIdx.x >> 7;
  float s = 0.f, s2 = 0.f;
  for (int r = blockIdx.x * 2 + half; r < n; r += gridDim.x * 2) {
    float v = h[(long)r * COUT + c];
    s += v; s2 += v * v;
  }
  __shared__ float ls[256], ls2[256];
  ls[threadIdx.x] = s; ls2[threadIdx.x] = s2;
  __syncthreads();
  if (half == 0) {
    s = ls[c] + ls[c + 128];
    s2 = ls2[c] + ls2[c + 128];
    atomicAdd(&stats[c], s);
    atomicAdd(&stats[128 + c], s2);
  }
}

__global__ void bn_elu_kernel(float* __restrict__ h, unsigned short* __restrict__ hb,
                              const float* __restrict__ stats, const float* __restrict__ g,
                              const float* __restrict__ be, int n) {
  long i = (long)blockIdx.x * 256 + threadIdx.x;
  if (i >= (long)n * COUT) return;
  int c = (int)(i & 127);
  float inv_n = 1.0f / n;
  float mu = stats[c] * inv_n;
  float var = stats[128 + c] * inv_n - mu * mu;
  float v = (h[i] - mu) * rsqrtf(var + EPS) * g[c] + be[c];
  v = v > 0.f ? v : expm1f(v);
  h[i] = v;
  hb[i] = f2b(v);
}

__global__ void xsum_kernel(const float* __restrict__ x, const int* __restrict__ rowptr,
                            const int* __restrict__ ssrc, unsigned short* __restrict__ xsb) {
  int node = blockIdx.x;
  int c = threadIdx.x; // 64 threads
  int b0 = rowptr[node], b1 = rowptr[node + 1];
  float s = 0.f;
  for (int e = b0; e < b1; e++) s += x[(long)ssrc[e] * CIN + c];
  float d = (float)(b1 - b0);
  s /= fmaxf(d, 1.0f);
  xsb[(long)node * CIN + c] = f2b(s);
}

__global__ void final_out_kernel(const float* __restrict__ h2, const float* __restrict__ sraw,
                                 const float* __restrict__ st2, const float* __restrict__ stsc,
                                 const float* __restrict__ g2, const float* __restrict__ be2,
                                 const float* __restrict__ gsc, const float* __restrict__ besc,
                                 float* __restrict__ out, int n) {
  long i = (long)blockIdx.x * 256 + threadIdx.x;
  if (i >= (long)n * COUT) return;
  int c = (int)(i & 127);
  float inv_n = 1.0f / n;
  float mu2 = st2[c] * inv_n;
  float var2 = st2[128 + c] * inv_n - mu2 * mu2;
  float a = (h2[i] - mu2) * rsqrtf(var2 + EPS) * g2[c] + be2[c];
  float musc = stsc[c] * inv_n;
  float varsc = stsc[128 + c] * inv_n - musc * musc;
  float b = (sraw[i] - musc) * rsqrtf(varsc + EPS) * gsc[c] + besc[c];
  float v = a + b;
  out[i] = v > 0.f ? v : expm1f(v);
}

// ---------------- host ----------------
extern "C" void kernel_launch(void* const* d_in, const int* in_sizes, int n_in,
                              void* d_out, int out_size, void* d_ws, size_t ws_size,
                              hipStream_t stream) {
  const float* x    = (const float*)d_in[0];
  const int*   eidx = (const int*)d_in[1];
  const float* attr = (const float*)d_in[2];
  const float* W1   = (const float*)d_in[3];
  const float* Wr1  = (const float*)d_in[4];
  const float* b1   = (const float*)d_in[5];
  const float* g1   = (const float*)d_in[6];
  const float* be1  = (const float*)d_in[7];
  const float* W2   = (const float*)d_in[8];
  const float* Wr2  = (const float*)d_in[9];
  const float* b2   = (const float*)d_in[10];
  const float* g2   = (const float*)d_in[11];
  const float* be2  = (const float*)d_in[12];
  const float* Wsc  = (const float*)d_in[13];
  const float* Wrsc = (const float*)d_in[14];
  const float* bsc  = (const float*)d_in[15];
  const float* gsc  = (const float*)d_in[16];
  const float* besc = (const float*)d_in[17];
  float* out = (float*)d_out;

  const int* src = eidx;
  const int* dst = eidx + N_EDGES;

  char* base = (char*)d_ws;
  size_t off = 0;
  auto alloc = [&](size_t bytes) -> char* {
    char* p = base + off;
    off += (bytes + 255) & ~(size_t)255;
    return p;
  };
  int* cnt    = (int*)alloc((size_t)N_NODES * 4);
  int* rowptr = (int*)alloc((size_t)(N_NODES + 1) * 4);
  int* cursor = (int*)alloc((size_t)N_NODES * 4);
  int* ssrc   = (int*)alloc((size_t)N_EDGES * 4);
  float* wts  = (float*)alloc((size_t)N_EDGES * 8 * 4);
  unsigned char* cidx = (unsigned char*)alloc((size_t)N_EDGES * 8);
  unsigned short* xb   = (unsigned short*)alloc((size_t)N_NODES * CIN * 2);
  unsigned short* hb   = (unsigned short*)alloc((size_t)N_NODES * COUT * 2);
  unsigned short* xsb  = (unsigned short*)alloc((size_t)N_NODES * CIN * 2);
  unsigned short* W1t  = (unsigned short*)alloc((size_t)COUT * KTOT * CIN * 2);
  unsigned short* W2t  = (unsigned short*)alloc((size_t)COUT * KTOT * COUT * 2);
  unsigned short* Wr1t = (unsigned short*)alloc((size_t)COUT * CIN * 2);
  unsigned short* Wr2t = (unsigned short*)alloc((size_t)COUT * COUT * 2);
  unsigned short* Wsct = (unsigned short*)alloc((size_t)COUT * CIN * 2);
  unsigned short* Wrsct= (unsigned short*)alloc((size_t)COUT * CIN * 2);
  float* msg   = (float*)alloc((size_t)N_NODES * COUT * 4);
  float* rootb = (float*)alloc((size_t)N_NODES * COUT * 4);
  float* h1    = (float*)alloc((size_t)N_NODES * COUT * 4);
  float* h2r   = (float*)alloc((size_t)N_NODES * COUT * 4);
  float* sraw  = (float*)alloc((size_t)N_NODES * COUT * 4);
  float* stats = (float*)alloc(6 * 128 * 4);
  unsigned short* accb = (unsigned short*)(base + off);
  size_t avail = (ws_size > off) ? (ws_size - off) : 0;
  size_t per_node = (size_t)KTOT * COUT * 2; // conv2 row: 32000 B
  size_t chmax = avail / per_node;
  int CH = (int)((chmax < (size_t)N_NODES) ? chmax : (size_t)N_NODES);
  if (CH < 1) CH = 1;

  hipMemsetAsync(cnt, 0, (size_t)N_NODES * 4, stream);
  hipMemsetAsync(cursor, 0, (size_t)N_NODES * 4, stream);
  hipMemsetAsync(stats, 0, 6 * 128 * 4, stream);

  count_kernel<<<CDIV(N_EDGES, 256), 256, 0, stream>>>(dst, cnt, N_EDGES);
  scan_kernel<<<1, 256, 0, stream>>>(cnt, rowptr, N_NODES);
  build_sorted<<<CDIV(N_EDGES, 256), 256, 0, stream>>>(src, dst, attr, rowptr, cursor,
                                                       ssrc, wts, cidx, N_EDGES);

  f2b_kernel<<<CDIV(N_NODES * CIN, 256), 256, 0, stream>>>(x, xb, (long)N_NODES * CIN);
  transpose_f2b<<<CDIV(KTOT * CIN * COUT, 256), 256, 0, stream>>>(W1, W1t, KTOT * CIN, COUT);
  transpose_f2b<<<CDIV(KTOT * COUT * COUT, 256), 256, 0, stream>>>(W2, W2t, KTOT * COUT, COUT);
  transpose_f2b<<<CDIV(CIN * COUT, 256), 256, 0, stream>>>(Wr1, Wr1t, CIN, COUT);
  transpose_f2b<<<CDIV(COUT * COUT, 256), 256, 0, stream>>>(Wr2, Wr2t, COUT, COUT);
  transpose_f2b<<<CDIV(CIN * COUT, 256), 256, 0, stream>>>(Wsc, Wsct, CIN, COUT);
  transpose_f2b<<<CDIV(CIN * COUT, 256), 256, 0, stream>>>(Wrsc, Wrsct, CIN, COUT);

  // ---- conv1 ----
  for (int c0 = 0; c0 < N_NODES; c0 += CH) {
    int cm = (N_NODES - c0 < CH) ? (N_NODES - c0) : CH;
    scatter_kernel<<<cm, 256, KTOT * CIN * 4, stream>>>(x, rowptr, ssrc, wts, cidx,
                                                        accb, c0, CIN);
    gemm_bf16<<<CDIV(cm, 64), 256, 0, stream>>>(accb, W1t, msg + (size_t)c0 * COUT,
                                                cm, KTOT * CIN);
  }
  gemm_bf16<<<CDIV(N_NODES, 64), 256, 0, stream>>>(xb, Wr1t, rootb, N_NODES, CIN);
  finalize_kernel<<<CDIV(N_NODES * COUT, 256), 256, 0, stream>>>(msg, rootb, b1, cnt,
                                                                 h1, N_NODES, 1);
  bn_stats<<<64, 256, 0, stream>>>(h1, stats, N_NODES);
  bn_elu_kernel<<<CDIV(N_NODES * COUT, 256), 256, 0, stream>>>(h1, hb, stats, g1, be1, N_NODES);

  // ---- conv2 ----
  for (int c0 = 0; c0 < N_NODES; c0 += CH) {
    int cm = (N_NODES - c0 < CH) ? (N_NODES - c0) : CH;
    scatter_kernel<<<cm, 256, KTOT * COUT * 4, stream>>>(h1, rowptr, ssrc, wts, cidx,
                                                         accb, c0, COUT);
    gemm_bf16<<<CDIV(cm, 64), 256, 0, stream>>>(accb, W2t, msg + (size_t)c0 * COUT,
                                                cm, KTOT * COUT);
  }
  gemm_bf16<<<CDIV(N_NODES, 64), 256, 0, stream>>>(hb, Wr2t, rootb, N_NODES, COUT);
  finalize_kernel<<<CDIV(N_NODES * COUT, 256), 256, 0, stream>>>(msg, rootb, b2, cnt,
                                                                 h2r, N_NODES, 1);
  bn_stats<<<64, 256, 0, stream>>>(h2r, stats + 256, N_NODES);

  // ---- shortcut ----
  xsum_kernel<<<N_NODES, 64, 0, stream>>>(x, rowptr, ssrc, xsb);
  gemm_bf16<<<CDIV(N_NODES, 64), 256, 0, stream>>>(xsb, Wsct, msg, N_NODES, CIN);
  gemm_bf16<<<CDIV(N_NODES, 64), 256, 0, stream>>>(xb, Wrsct, rootb, N_NODES, CIN);
  finalize_kernel<<<CDIV(N_NODES * COUT, 256), 256, 0, stream>>>(msg, rootb, bsc, cnt,
                                                                 sraw, N_NODES, 0);
  bn_stats<<<64, 256, 0, stream>>>(sraw, stats + 512, N_NODES);

  // ---- output ----
  final_out_kernel<<<CDIV(N_NODES * COUT, 256), 256, 0, stream>>>(
      h2r, sraw, stats + 256, stats + 512, g2, be2, gsc, besc, out, N_NODES);
}

// Round 2
// 1989.183 us; speedup vs baseline: 2.1831x; 2.1831x over previous
//
#include <hip/hip_runtime.h>

#define N_NODES 10000
#define N_EDGES 160000
#define CIN 64
#define COUT 128
#define KTOT 125
#define EPS 1e-5f

#define CDIV(a,b) (((a)+(b)-1)/(b))

typedef __attribute__((ext_vector_type(8))) short short8;
typedef __attribute__((ext_vector_type(4))) float floatx4;

static __device__ __forceinline__ unsigned short f2b(float f) {
  union { float f; unsigned u; } v; v.f = f;
  unsigned r = v.u + 0x7FFFu + ((v.u >> 16) & 1u);
  return (unsigned short)(r >> 16);
}

typedef __attribute__((address_space(1))) const unsigned int guint;
typedef __attribute__((address_space(3))) unsigned int luint;
static __device__ __forceinline__ void ld_g2l16(const void* g, void* l) {
  __builtin_amdgcn_global_load_lds((guint*)g, (luint*)l, 16, 0, 0);
}

// ---------------- CSR build ----------------
__global__ void count_kernel(const int* __restrict__ dst, int* __restrict__ cnt, int E) {
  int e = blockIdx.x * 256 + threadIdx.x;
  if (e < E) atomicAdd(&cnt[dst[e]], 1);
}

__global__ void scan_kernel(const int* __restrict__ cnt, int* __restrict__ rowptr, int n) {
  __shared__ int buf[256];
  __shared__ int carry;
  if (threadIdx.x == 0) { carry = 0; rowptr[0] = 0; }
  __syncthreads();
  for (int base = 0; base < n; base += 256) {
    int i = base + threadIdx.x;
    int v = (i < n) ? cnt[i] : 0;
    buf[threadIdx.x] = v;
    __syncthreads();
    for (int s = 1; s < 256; s <<= 1) {
      int t = (threadIdx.x >= s) ? buf[threadIdx.x - s] : 0;
      __syncthreads();
      buf[threadIdx.x] += t;
      __syncthreads();
    }
    if (i < n) rowptr[i + 1] = carry + buf[threadIdx.x];
    __syncthreads();
    if (threadIdx.x == 255) carry += buf[255];
    __syncthreads();
  }
}

__global__ void build_sorted(const int* __restrict__ src, const int* __restrict__ dst,
                             const float* __restrict__ attr, const int* __restrict__ rowptr,
                             int* __restrict__ cursor, int* __restrict__ ssrc,
                             float* __restrict__ wts, unsigned char* __restrict__ cidx, int E) {
  int e = blockIdx.x * 256 + threadIdx.x;
  if (e >= E) return;
  int d = dst[e];
  int pos = rowptr[d] + atomicAdd(&cursor[d], 1);
  ssrc[pos] = src[e];
  float v0 = attr[e * 3 + 0] * 4.f;
  float v1 = attr[e * 3 + 1] * 4.f;
  float v2 = attr[e * 3 + 2] * 4.f;
  float b0f = floorf(v0), b1f = floorf(v1), b2f = floorf(v2);
  float f0 = v0 - b0f, f1 = v1 - b1f, f2 = v2 - b2f;
  int i0 = (int)b0f, i1 = (int)b1f, i2 = (int)b2f;
#pragma unroll
  for (int combo = 0; combo < 8; combo++) {
    int bit0 = combo & 1, bit1 = (combo >> 1) & 1, bit2 = (combo >> 2) & 1;
    float w = (bit0 ? f0 : 1.f - f0) * (bit1 ? f1 : 1.f - f1) * (bit2 ? f2 : 1.f - f2);
    int k0 = min(max(i0 + bit0, 0), 4);
    int k1 = min(max(i1 + bit1, 0), 4);
    int k2 = min(max(i2 + bit2, 0), 4);
    cidx[(long)pos * 8 + combo] = (unsigned char)(k0 * 25 + k1 * 5 + k2);
    wts[(long)pos * 8 + combo] = w;
  }
}

// ---------------- converts ----------------
__global__ void f2b_kernel(const float* __restrict__ in, unsigned short* __restrict__ out, long n) {
  long i = (long)blockIdx.x * 256 + threadIdx.x;
  if (i < n) out[i] = f2b(in[i]);
}

// in: fp32 [K][C] row-major  ->  out: bf16 [C][K]
__global__ void transpose_f2b(const float* __restrict__ in, unsigned short* __restrict__ out,
                              int K, int C) {
  long i = (long)blockIdx.x * 256 + threadIdx.x;
  long tot = (long)K * C;
  if (i >= tot) return;
  int k = (int)(i / C), c = (int)(i % C);
  out[(long)c * K + k] = f2b(in[i]);
}

// ---------------- scatter: per-node LDS accumulate -> bf16 acc rows ----------------
__global__ void scatter_kernel(const float* __restrict__ X, const int* __restrict__ rowptr,
                               const int* __restrict__ ssrc, const float* __restrict__ wts,
                               const unsigned char* __restrict__ cidx,
                               unsigned short* __restrict__ accb, int chunk0, int cin) {
  int node = chunk0 + blockIdx.x;
  extern __shared__ float accs[];
  int tot = KTOT * cin;
  for (int i = threadIdx.x; i < tot; i += 256) accs[i] = 0.f;
  __syncthreads();
  int b0 = rowptr[node], b1 = rowptr[node + 1];
  int lane_c = threadIdx.x & (cin - 1);
  int sub = threadIdx.x / cin;
  int epb = 256 / cin;
  for (int e = b0 + sub; e < b1; e += epb) {
    float xv = X[(long)ssrc[e] * cin + lane_c];
#pragma unroll
    for (int c = 0; c < 8; c++) {
      float w = wts[(long)e * 8 + c];
      int k = cidx[(long)e * 8 + c];
      atomicAdd(&accs[k * cin + lane_c], w * xv);
    }
  }
  __syncthreads();
  unsigned short* dstp = accb + (long)blockIdx.x * tot;
  for (int i = threadIdx.x; i < tot; i += 256) dstp[i] = f2b(accs[i]);
}

// ---------------- LDS-staged MFMA GEMM: C[M,128] (+)= A[M,K] * Bt[128,K]^T ----------
// 128x128 block tile, BK=32, global_load_lds width=16, optional split-K w/ atomics.
template<bool ATOMIC>
__global__ __launch_bounds__(256, 2) void gemm_tile(const unsigned short* __restrict__ A,
                                                    const unsigned short* __restrict__ Bt,
                                                    float* __restrict__ C, int M, int K) {
  __shared__ unsigned short As[128 * 32];
  __shared__ unsigned short Bs[128 * 32];
  int wid = threadIdx.x >> 6, lane = threadIdx.x & 63;
  int row0 = blockIdx.x * 128;
  int nslice = gridDim.y;
  int kslice = CDIV(K / 32, nslice) * 32;
  int kbeg = blockIdx.y * kslice;
  int kend = kbeg + kslice; if (kend > K) kend = K;
  if (kbeg >= K) return;

  int sub = lane & 3;          // which 16B chunk of a 64B row
  int rload = lane >> 2;       // 16 rows per wave-load
  int q = lane >> 4, m16 = lane & 15;

  floatx4 acc[2][8];
#pragma unroll
  for (int t = 0; t < 2; t++)
#pragma unroll
    for (int c = 0; c < 8; c++) acc[t][c] = (floatx4){0.f, 0.f, 0.f, 0.f};

  for (int k0 = kbeg; k0 < kend; k0 += 32) {
    __syncthreads();
#pragma unroll
    for (int j = 0; j < 2; j++) {
      int tr = (wid * 2 + j) * 16 + rload;
      int gr = row0 + tr; if (gr >= M) gr = M - 1;
      ld_g2l16(A + (long)gr * K + k0 + sub * 8, As + (wid * 2 + j) * 512);
      ld_g2l16(Bt + (long)tr * K + k0 + sub * 8, Bs + (wid * 2 + j) * 512);
    }
    __syncthreads();
#pragma unroll
    for (int t = 0; t < 2; t++) {
      int arow = wid * 32 + t * 16 + m16;
      short8 a = *(const short8*)(As + arow * 32 + q * 8);
#pragma unroll
      for (int c = 0; c < 8; c++) {
        short8 b = *(const short8*)(Bs + (c * 16 + m16) * 32 + q * 8);
        acc[t][c] = __builtin_amdgcn_mfma_f32_16x16x32_bf16(a, b, acc[t][c], 0, 0, 0);
      }
    }
  }

#pragma unroll
  for (int t = 0; t < 2; t++) {
#pragma unroll
    for (int c = 0; c < 8; c++) {
#pragma unroll
      for (int r = 0; r < 4; r++) {
        int orow = row0 + wid * 32 + t * 16 + q * 4 + r;
        if (orow < M) {
          float* p = &C[(long)orow * COUT + c * 16 + m16];
          if (ATOMIC) atomicAdd(p, acc[t][c][r]);
          else *p = acc[t][c][r];
        }
      }
    }
  }
}

// ---------------- epilogues ----------------
__global__ void finalize_kernel(const float* __restrict__ msg, const float* __restrict__ root,
                                const float* __restrict__ bias, const int* __restrict__ deg,
                                float* __restrict__ out, int n, int divide) {
  long i = (long)blockIdx.x * 256 + threadIdx.x;
  if (i >= (long)n * COUT) return;
  int r = (int)(i >> 7), c = (int)(i & 127);
  float mv = msg[i];
  if (divide) { float d = (float)deg[r]; mv = mv / fmaxf(d, 1.0f); }
  out[i] = mv + root[i] + bias[c];
}

__global__ void bn_stats(const float* __restrict__ h, float* __restrict__ stats, int n) {
  int c = threadIdx.x & 127;
  int half = threadIdx.x >> 7;
  float s = 0.f, s2 = 0.f;
  for (int r = blockIdx.x * 2 + half; r < n; r += gridDim.x * 2) {
    float v = h[(long)r * COUT + c];
    s += v; s2 += v * v;
  }
  __shared__ float ls[256], ls2[256];
  ls[threadIdx.x] = s; ls2[threadIdx.x] = s2;
  __syncthreads();
  if (half == 0) {
    s = ls[c] + ls[c + 128];
    s2 = ls2[c] + ls2[c + 128];
    atomicAdd(&stats[c], s);
    atomicAdd(&stats[128 + c], s2);
  }
}

__global__ void bn_elu_kernel(float* __restrict__ h, unsigned short* __restrict__ hb,
                              const float* __restrict__ stats, const float* __restrict__ g,
                              const float* __restrict__ be, int n) {
  long i = (long)blockIdx.x * 256 + threadIdx.x;
  if (i >= (long)n * COUT) return;
  int c = (int)(i & 127);
  float inv_n = 1.0f / n;
  float mu = stats[c] * inv_n;
  float var = stats[128 + c] * inv_n - mu * mu;
  float v = (h[i] - mu) * rsqrtf(var + EPS) * g[c] + be[c];
  v = v > 0.f ? v : expm1f(v);
  h[i] = v;
  hb[i] = f2b(v);
}

__global__ void xsum_kernel(const float* __restrict__ x, const int* __restrict__ rowptr,
                            const int* __restrict__ ssrc, unsigned short* __restrict__ xsb) {
  int node = blockIdx.x;
  int c = threadIdx.x; // 64 threads
  int b0 = rowptr[node], b1 = rowptr[node + 1];
  float s = 0.f;
  for (int e = b0; e < b1; e++) s += x[(long)ssrc[e] * CIN + c];
  float d = (float)(b1 - b0);
  s /= fmaxf(d, 1.0f);
  xsb[(long)node * CIN + c] = f2b(s);
}

__global__ void final_out_kernel(const float* __restrict__ h2, const float* __restrict__ sraw,
                                 const float* __restrict__ st2, const float* __restrict__ stsc,
                                 const float* __restrict__ g2, const float* __restrict__ be2,
                                 const float* __restrict__ gsc, const float* __restrict__ besc,
                                 float* __restrict__ out, int n) {
  long i = (long)blockIdx.x * 256 + threadIdx.x;
  if (i >= (long)n * COUT) return;
  int c = (int)(i & 127);
  float inv_n = 1.0f / n;
  float mu2 = st2[c] * inv_n;
  float var2 = st2[128 + c] * inv_n - mu2 * mu2;
  float a = (h2[i] - mu2) * rsqrtf(var2 + EPS) * g2[c] + be2[c];
  float musc = stsc[c] * inv_n;
  float varsc = stsc[128 + c] * inv_n - musc * musc;
  float b = (sraw[i] - musc) * rsqrtf(varsc + EPS) * gsc[c] + besc[c];
  float v = a + b;
  out[i] = v > 0.f ? v : expm1f(v);
}

// ---------------- host ----------------
extern "C" void kernel_launch(void* const* d_in, const int* in_sizes, int n_in,
                              void* d_out, int out_size, void* d_ws, size_t ws_size,
                              hipStream_t stream) {
  const float* x    = (const float*)d_in[0];
  const int*   eidx = (const int*)d_in[1];
  const float* attr = (const float*)d_in[2];
  const float* W1   = (const float*)d_in[3];
  const float* Wr1  = (const float*)d_in[4];
  const float* b1   = (const float*)d_in[5];
  const float* g1   = (const float*)d_in[6];
  const float* be1  = (const float*)d_in[7];
  const float* W2   = (const float*)d_in[8];
  const float* Wr2  = (const float*)d_in[9];
  const float* b2   = (const float*)d_in[10];
  const float* g2   = (const float*)d_in[11];
  const float* be2  = (const float*)d_in[12];
  const float* Wsc  = (const float*)d_in[13];
  const float* Wrsc = (const float*)d_in[14];
  const float* bsc  = (const float*)d_in[15];
  const float* gsc  = (const float*)d_in[16];
  const float* besc = (const float*)d_in[17];
  float* out = (float*)d_out;

  const int* src = eidx;
  const int* dst = eidx + N_EDGES;

  char* base = (char*)d_ws;
  size_t off = 0;
  auto alloc = [&](size_t bytes) -> char* {
    char* p = base + off;
    off += (bytes + 255) & ~(size_t)255;
    return p;
  };
  int* cnt    = (int*)alloc((size_t)N_NODES * 4);
  int* rowptr = (int*)alloc((size_t)(N_NODES + 1) * 4);
  int* cursor = (int*)alloc((size_t)N_NODES * 4);
  int* ssrc   = (int*)alloc((size_t)N_EDGES * 4);
  float* wts  = (float*)alloc((size_t)N_EDGES * 8 * 4);
  unsigned char* cidx = (unsigned char*)alloc((size_t)N_EDGES * 8);
  unsigned short* xb   = (unsigned short*)alloc((size_t)N_NODES * CIN * 2);
  unsigned short* hb   = (unsigned short*)alloc((size_t)N_NODES * COUT * 2);
  unsigned short* xsb  = (unsigned short*)alloc((size_t)N_NODES * CIN * 2);
  unsigned short* W1t  = (unsigned short*)alloc((size_t)COUT * KTOT * CIN * 2);
  unsigned short* W2t  = (unsigned short*)alloc((size_t)COUT * KTOT * COUT * 2);
  unsigned short* Wr1t = (unsigned short*)alloc((size_t)COUT * CIN * 2);
  unsigned short* Wr2t = (unsigned short*)alloc((size_t)COUT * COUT * 2);
  unsigned short* Wsct = (unsigned short*)alloc((size_t)COUT * CIN * 2);
  unsigned short* Wrsct= (unsigned short*)alloc((size_t)COUT * CIN * 2);
  float* msg   = (float*)alloc((size_t)N_NODES * COUT * 4);
  float* rootb = (float*)alloc((size_t)N_NODES * COUT * 4);
  float* h1    = (float*)alloc((size_t)N_NODES * COUT * 4);
  float* h2r   = (float*)alloc((size_t)N_NODES * COUT * 4);
  float* sraw  = (float*)alloc((size_t)N_NODES * COUT * 4);
  float* stats = (float*)alloc(6 * 128 * 4);
  unsigned short* accb = (unsigned short*)(base + off);
  size_t avail = (ws_size > off) ? (ws_size - off) : 0;
  size_t per_node = (size_t)KTOT * COUT * 2; // conv2 row: 32000 B
  size_t chmax = avail / per_node;
  int CH = (int)((chmax < (size_t)N_NODES) ? chmax : (size_t)N_NODES);
  if (CH < 1) CH = 1;
  const int SPLIT = 10; // 8000/10=800, 16000/10=1600 -- both multiples of 32

  hipMemsetAsync(cnt, 0, (size_t)N_NODES * 4, stream);
  hipMemsetAsync(cursor, 0, (size_t)N_NODES * 4, stream);
  hipMemsetAsync(stats, 0, 6 * 128 * 4, stream);

  count_kernel<<<CDIV(N_EDGES, 256), 256, 0, stream>>>(dst, cnt, N_EDGES);
  scan_kernel<<<1, 256, 0, stream>>>(cnt, rowptr, N_NODES);
  build_sorted<<<CDIV(N_EDGES, 256), 256, 0, stream>>>(src, dst, attr, rowptr, cursor,
                                                       ssrc, wts, cidx, N_EDGES);

  f2b_kernel<<<CDIV(N_NODES * CIN, 256), 256, 0, stream>>>(x, xb, (long)N_NODES * CIN);
  transpose_f2b<<<CDIV(KTOT * CIN * COUT, 256), 256, 0, stream>>>(W1, W1t, KTOT * CIN, COUT);
  transpose_f2b<<<CDIV(KTOT * COUT * COUT, 256), 256, 0, stream>>>(W2, W2t, KTOT * COUT, COUT);
  transpose_f2b<<<CDIV(CIN * COUT, 256), 256, 0, stream>>>(Wr1, Wr1t, CIN, COUT);
  transpose_f2b<<<CDIV(COUT * COUT, 256), 256, 0, stream>>>(Wr2, Wr2t, COUT, COUT);
  transpose_f2b<<<CDIV(CIN * COUT, 256), 256, 0, stream>>>(Wsc, Wsct, CIN, COUT);
  transpose_f2b<<<CDIV(CIN * COUT, 256), 256, 0, stream>>>(Wrsc, Wrsct, CIN, COUT);

  // ---- conv1 ----
  hipMemsetAsync(msg, 0, (size_t)N_NODES * COUT * 4, stream);
  for (int c0 = 0; c0 < N_NODES; c0 += CH) {
    int cm = (N_NODES - c0 < CH) ? (N_NODES - c0) : CH;
    scatter_kernel<<<cm, 256, KTOT * CIN * 4, stream>>>(x, rowptr, ssrc, wts, cidx,
                                                        accb, c0, CIN);
    dim3 g(CDIV(cm, 128), SPLIT);
    gemm_tile<true><<<g, 256, 0, stream>>>(accb, W1t, msg + (size_t)c0 * COUT,
                                           cm, KTOT * CIN);
  }
  gemm_tile<false><<<dim3(CDIV(N_NODES, 128), 1), 256, 0, stream>>>(xb, Wr1t, rootb,
                                                                    N_NODES, CIN);
  finalize_kernel<<<CDIV(N_NODES * COUT, 256), 256, 0, stream>>>(msg, rootb, b1, cnt,
                                                                 h1, N_NODES, 1);
  bn_stats<<<64, 256, 0, stream>>>(h1, stats, N_NODES);
  bn_elu_kernel<<<CDIV(N_NODES * COUT, 256), 256, 0, stream>>>(h1, hb, stats, g1, be1, N_NODES);

  // ---- conv2 ----
  hipMemsetAsync(msg, 0, (size_t)N_NODES * COUT * 4, stream);
  for (int c0 = 0; c0 < N_NODES; c0 += CH) {
    int cm = (N_NODES - c0 < CH) ? (N_NODES - c0) : CH;
    scatter_kernel<<<cm, 256, KTOT * COUT * 4, stream>>>(h1, rowptr, ssrc, wts, cidx,
                                                         accb, c0, COUT);
    dim3 g(CDIV(cm, 128), SPLIT);
    gemm_tile<true><<<g, 256, 0, stream>>>(accb, W2t, msg + (size_t)c0 * COUT,
                                           cm, KTOT * COUT);
  }
  gemm_tile<false><<<dim3(CDIV(N_NODES, 128), 1), 256, 0, stream>>>(hb, Wr2t, rootb,
                                                                    N_NODES, COUT);
  finalize_kernel<<<CDIV(N_NODES * COUT, 256), 256, 0, stream>>>(msg, rootb, b2, cnt,
                                                                 h2r, N_NODES, 1);
  bn_stats<<<64, 256, 0, stream>>>(h2r, stats + 256, N_NODES);

  // ---- shortcut ----
  xsum_kernel<<<N_NODES, 64, 0, stream>>>(x, rowptr, ssrc, xsb);
  gemm_tile<false><<<dim3(CDIV(N_NODES, 128), 1), 256, 0, stream>>>(xsb, Wsct, msg,
                                                                    N_NODES, CIN);
  gemm_tile<false><<<dim3(CDIV(N_NODES, 128), 1), 256, 0, stream>>>(xb, Wrsct, rootb,
                                                                    N_NODES, CIN);
  finalize_kernel<<<CDIV(N_NODES * COUT, 256), 256, 0, stream>>>(msg, rootb, bsc, cnt,
                                                                 sraw, N_NODES, 0);
  bn_stats<<<64, 256, 0, stream>>>(sraw, stats + 512, N_NODES);

  // ---- output ----
  final_out_kernel<<<CDIV(N_NODES * COUT, 256), 256, 0, stream>>>(
      h2r, sraw, stats + 256, stats + 512, g2, be2, gsc, besc, out, N_NODES);
}

// Round 3
// 1941.826 us; speedup vs baseline: 2.2364x; 1.0244x over previous
//
#include <hip/hip_runtime.h>

#define N_NODES 10000
#define N_EDGES 160000
#define CIN 64
#define COUT 128
#define KTOT 125
#define EPS 1e-5f

#define CDIV(a,b) (((a)+(b)-1)/(b))

typedef __attribute__((ext_vector_type(8))) short short8;
typedef __attribute__((ext_vector_type(4))) float floatx4;

static __device__ __forceinline__ unsigned short f2b(float f) {
  union { float f; unsigned u; } v; v.f = f;
  unsigned r = v.u + 0x7FFFu + ((v.u >> 16) & 1u);
  return (unsigned short)(r >> 16);
}
static __device__ __forceinline__ float b2f(unsigned short u) {
  union { unsigned u; float f; } v; v.u = ((unsigned)u) << 16;
  return v.f;
}

typedef __attribute__((address_space(1))) const unsigned int guint;
typedef __attribute__((address_space(3))) unsigned int luint;
static __device__ __forceinline__ void ld_g2l16(const void* g, void* l) {
  __builtin_amdgcn_global_load_lds((guint*)g, (luint*)l, 16, 0, 0);
}

// ---------------- CSR build ----------------
__global__ void count_kernel(const int* __restrict__ dst, int* __restrict__ cnt, int E) {
  int e = blockIdx.x * 256 + threadIdx.x;
  if (e < E) atomicAdd(&cnt[dst[e]], 1);
}

__global__ void scan_kernel(const int* __restrict__ cnt, int* __restrict__ rowptr, int n) {
  __shared__ int buf[256];
  __shared__ int carry;
  if (threadIdx.x == 0) { carry = 0; rowptr[0] = 0; }
  __syncthreads();
  for (int base = 0; base < n; base += 256) {
    int i = base + threadIdx.x;
    int v = (i < n) ? cnt[i] : 0;
    buf[threadIdx.x] = v;
    __syncthreads();
    for (int s = 1; s < 256; s <<= 1) {
      int t = (threadIdx.x >= s) ? buf[threadIdx.x - s] : 0;
      __syncthreads();
      buf[threadIdx.x] += t;
      __syncthreads();
    }
    if (i < n) rowptr[i + 1] = carry + buf[threadIdx.x];
    __syncthreads();
    if (threadIdx.x == 255) carry += buf[255];
    __syncthreads();
  }
}

__global__ void build_sorted(const int* __restrict__ src, const int* __restrict__ dst,
                             const float* __restrict__ attr, const int* __restrict__ rowptr,
                             int* __restrict__ cursor, int* __restrict__ ssrc,
                             float* __restrict__ wts, unsigned char* __restrict__ cidx, int E) {
  int e = blockIdx.x * 256 + threadIdx.x;
  if (e >= E) return;
  int d = dst[e];
  int pos = rowptr[d] + atomicAdd(&cursor[d], 1);
  ssrc[pos] = src[e];
  float v0 = attr[e * 3 + 0] * 4.f;
  float v1 = attr[e * 3 + 1] * 4.f;
  float v2 = attr[e * 3 + 2] * 4.f;
  float b0f = floorf(v0), b1f = floorf(v1), b2f_ = floorf(v2);
  float f0 = v0 - b0f, f1 = v1 - b1f, f2 = v2 - b2f_;
  int i0 = (int)b0f, i1 = (int)b1f, i2 = (int)b2f_;
#pragma unroll
  for (int combo = 0; combo < 8; combo++) {
    int bit0 = combo & 1, bit1 = (combo >> 1) & 1, bit2 = (combo >> 2) & 1;
    float w = (bit0 ? f0 : 1.f - f0) * (bit1 ? f1 : 1.f - f1) * (bit2 ? f2 : 1.f - f2);
    int k0 = min(max(i0 + bit0, 0), 4);
    int k1 = min(max(i1 + bit1, 0), 4);
    int k2 = min(max(i2 + bit2, 0), 4);
    cidx[(long)pos * 8 + combo] = (unsigned char)(k0 * 25 + k1 * 5 + k2);
    wts[(long)pos * 8 + combo] = w;
  }
}

// ---------------- converts ----------------
__global__ void f2b_kernel(const float* __restrict__ in, unsigned short* __restrict__ out, long n) {
  long i = (long)blockIdx.x * 256 + threadIdx.x;
  if (i < n) out[i] = f2b(in[i]);
}

// in: fp32 [K][C] row-major  ->  out: bf16 [C][K]
__global__ void transpose_f2b(const float* __restrict__ in, unsigned short* __restrict__ out,
                              int K, int C) {
  long i = (long)blockIdx.x * 256 + threadIdx.x;
  long tot = (long)K * C;
  if (i >= tot) return;
  int k = (int)(i / C), c = (int)(i % C);
  out[(long)c * K + k] = f2b(in[i]);
}

// ---------------- scatter: per-(node, 64ch) LDS accumulate -> bf16 acc rows ----------
// grid: (nodes_in_chunk, cin/64). LDS 32 KB -> 5 blocks/CU, 4 edges in flight.
__global__ __launch_bounds__(256, 5) void scatter_kernel(
    const unsigned short* __restrict__ Xb, const int* __restrict__ rowptr,
    const int* __restrict__ ssrc, const float* __restrict__ wts,
    const unsigned char* __restrict__ cidx,
    unsigned short* __restrict__ accb, int chunk0, int cin) {
  int node = chunk0 + blockIdx.x;
  int c0 = blockIdx.y * 64;
  __shared__ float accs[KTOT * 64];
  floatx4* av = (floatx4*)accs;
  for (int i = threadIdx.x; i < KTOT * 16; i += 256)
    av[i] = (floatx4){0.f, 0.f, 0.f, 0.f};
  __syncthreads();
  int b0 = rowptr[node], b1 = rowptr[node + 1];
  int lane = threadIdx.x & 63;
  int sub = threadIdx.x >> 6;
  for (int e = b0 + sub; e < b1; e += 4) {
    float xv = b2f(Xb[(long)ssrc[e] * cin + c0 + lane]);
    const float* wp = wts + (long)e * 8;
    const unsigned char* cp = cidx + (long)e * 8;
#pragma unroll
    for (int c = 0; c < 8; c++) {
      atomicAdd(&accs[(int)cp[c] * 64 + lane], wp[c] * xv);
    }
  }
  __syncthreads();
  unsigned short* dstp = accb + (long)blockIdx.x * KTOT * cin + c0;
  for (int i = threadIdx.x; i < KTOT * 16; i += 256) {
    int k = i >> 4, cc = (i & 15) * 4;
    floatx4 v = *(floatx4*)&accs[k * 64 + cc];
    unsigned int p0 = (unsigned)f2b(v[0]) | ((unsigned)f2b(v[1]) << 16);
    unsigned int p1 = (unsigned)f2b(v[2]) | ((unsigned)f2b(v[3]) << 16);
    unsigned int* gp = (unsigned int*)(dstp + (long)k * cin + cc);
    gp[0] = p0; gp[1] = p1;
  }
}

// ---------------- LDS-staged MFMA GEMM: C[M,128] (+)= A[M,K] * Bt[128,K]^T ----------
template<bool ATOMIC>
__global__ __launch_bounds__(256, 2) void gemm_tile(const unsigned short* __restrict__ A,
                                                    const unsigned short* __restrict__ Bt,
                                                    float* __restrict__ C, int M, int K) {
  __shared__ unsigned short As[128 * 32];
  __shared__ unsigned short Bs[128 * 32];
  int wid = threadIdx.x >> 6, lane = threadIdx.x & 63;
  int row0 = blockIdx.x * 128;
  int nslice = gridDim.y;
  int kslice = CDIV(K / 32, nslice) * 32;
  int kbeg = blockIdx.y * kslice;
  int kend = kbeg + kslice; if (kend > K) kend = K;
  if (kbeg >= K) return;

  int sub = lane & 3;
  int rload = lane >> 2;
  int q = lane >> 4, m16 = lane & 15;

  floatx4 acc[2][8];
#pragma unroll
  for (int t = 0; t < 2; t++)
#pragma unroll
    for (int c = 0; c < 8; c++) acc[t][c] = (floatx4){0.f, 0.f, 0.f, 0.f};

  for (int k0 = kbeg; k0 < kend; k0 += 32) {
    __syncthreads();
#pragma unroll
    for (int j = 0; j < 2; j++) {
      int tr = (wid * 2 + j) * 16 + rload;
      int gr = row0 + tr; if (gr >= M) gr = M - 1;
      ld_g2l16(A + (long)gr * K + k0 + sub * 8, As + (wid * 2 + j) * 512);
      ld_g2l16(Bt + (long)tr * K + k0 + sub * 8, Bs + (wid * 2 + j) * 512);
    }
    __syncthreads();
#pragma unroll
    for (int t = 0; t < 2; t++) {
      int arow = wid * 32 + t * 16 + m16;
      short8 a = *(const short8*)(As + arow * 32 + q * 8);
#pragma unroll
      for (int c = 0; c < 8; c++) {
        short8 b = *(const short8*)(Bs + (c * 16 + m16) * 32 + q * 8);
        acc[t][c] = __builtin_amdgcn_mfma_f32_16x16x32_bf16(a, b, acc[t][c], 0, 0, 0);
      }
    }
  }

#pragma unroll
  for (int t = 0; t < 2; t++) {
#pragma unroll
    for (int c = 0; c < 8; c++) {
#pragma unroll
      for (int r = 0; r < 4; r++) {
        int orow = row0 + wid * 32 + t * 16 + q * 4 + r;
        if (orow < M) {
          float* p = &C[(long)orow * COUT + c * 16 + m16];
          if (ATOMIC) atomicAdd(p, acc[t][c][r]);
          else *p = acc[t][c][r];
        }
      }
    }
  }
}

// ---------------- epilogues ----------------
// fused finalize + batch-stat accumulation. Launch with 64 blocks x 256
// (stride 16384, multiple of 128 -> each thread's channel is fixed).
__global__ void finalize_stats(const float* __restrict__ msg, const float* __restrict__ root,
                               const float* __restrict__ bias, const int* __restrict__ deg,
                               float* __restrict__ out, float* __restrict__ stats,
                               int n, int divide) {
  int c = threadIdx.x & 127;
  float bv = bias[c];
  float s = 0.f, s2 = 0.f;
  long tot = (long)n * COUT;
  long stride = (long)gridDim.x * 256;
  for (long i = (long)blockIdx.x * 256 + threadIdx.x; i < tot; i += stride) {
    int r = (int)(i >> 7);
    float mv = msg[i];
    if (divide) mv /= fmaxf((float)deg[r], 1.0f);
    float v = mv + root[i] + bv;
    out[i] = v;
    s += v; s2 += v * v;
  }
  __shared__ float ls[256], ls2[256];
  ls[threadIdx.x] = s; ls2[threadIdx.x] = s2;
  __syncthreads();
  if (threadIdx.x < 128) {
    atomicAdd(&stats[c], ls[threadIdx.x] + ls[threadIdx.x + 128]);
    atomicAdd(&stats[128 + c], ls2[threadIdx.x] + ls2[threadIdx.x + 128]);
  }
}

__global__ void bn_elu_kernel(float* __restrict__ h, unsigned short* __restrict__ hb,
                              const float* __restrict__ stats, const float* __restrict__ g,
                              const float* __restrict__ be, int n) {
  long i = (long)blockIdx.x * 256 + threadIdx.x;
  if (i >= (long)n * COUT) return;
  int c = (int)(i & 127);
  float inv_n = 1.0f / n;
  float mu = stats[c] * inv_n;
  float var = stats[128 + c] * inv_n - mu * mu;
  float v = (h[i] - mu) * rsqrtf(var + EPS) * g[c] + be[c];
  v = v > 0.f ? v : expm1f(v);
  h[i] = v;
  hb[i] = f2b(v);
}

__global__ void xsum_kernel(const float* __restrict__ x, const int* __restrict__ rowptr,
                            const int* __restrict__ ssrc, unsigned short* __restrict__ xsb) {
  int node = blockIdx.x;
  int c = threadIdx.x; // 64 threads
  int b0 = rowptr[node], b1 = rowptr[node + 1];
  float s = 0.f;
  for (int e = b0; e < b1; e++) s += x[(long)ssrc[e] * CIN + c];
  float d = (float)(b1 - b0);
  s /= fmaxf(d, 1.0f);
  xsb[(long)node * CIN + c] = f2b(s);
}

__global__ void final_out_kernel(const float* __restrict__ h2, const float* __restrict__ sraw,
                                 const float* __restrict__ st2, const float* __restrict__ stsc,
                                 const float* __restrict__ g2, const float* __restrict__ be2,
                                 const float* __restrict__ gsc, const float* __restrict__ besc,
                                 float* __restrict__ out, int n) {
  long i = (long)blockIdx.x * 256 + threadIdx.x;
  if (i >= (long)n * COUT) return;
  int c = (int)(i & 127);
  float inv_n = 1.0f / n;
  float mu2 = st2[c] * inv_n;
  float var2 = st2[128 + c] * inv_n - mu2 * mu2;
  float a = (h2[i] - mu2) * rsqrtf(var2 + EPS) * g2[c] + be2[c];
  float musc = stsc[c] * inv_n;
  float varsc = stsc[128 + c] * inv_n - musc * musc;
  float b = (sraw[i] - musc) * rsqrtf(varsc + EPS) * gsc[c] + besc[c];
  float v = a + b;
  out[i] = v > 0.f ? v : expm1f(v);
}

// ---------------- host ----------------
extern "C" void kernel_launch(void* const* d_in, const int* in_sizes, int n_in,
                              void* d_out, int out_size, void* d_ws, size_t ws_size,
                              hipStream_t stream) {
  const float* x    = (const float*)d_in[0];
  const int*   eidx = (const int*)d_in[1];
  const float* attr = (const float*)d_in[2];
  const float* W1   = (const float*)d_in[3];
  const float* Wr1  = (const float*)d_in[4];
  const float* b1   = (const float*)d_in[5];
  const float* g1   = (const float*)d_in[6];
  const float* be1  = (const float*)d_in[7];
  const float* W2   = (const float*)d_in[8];
  const float* Wr2  = (const float*)d_in[9];
  const float* b2   = (const float*)d_in[10];
  const float* g2   = (const float*)d_in[11];
  const float* be2  = (const float*)d_in[12];
  const float* Wsc  = (const float*)d_in[13];
  const float* Wrsc = (const float*)d_in[14];
  const float* bsc  = (const float*)d_in[15];
  const float* gsc  = (const float*)d_in[16];
  const float* besc = (const float*)d_in[17];
  float* out = (float*)d_out;

  const int* src = eidx;
  const int* dst = eidx + N_EDGES;

  char* base = (char*)d_ws;
  size_t off = 0;
  auto alloc = [&](size_t bytes) -> char* {
    char* p = base + off;
    off += (bytes + 255) & ~(size_t)255;
    return p;
  };
  int* cnt    = (int*)alloc((size_t)N_NODES * 4);
  int* rowptr = (int*)alloc((size_t)(N_NODES + 1) * 4);
  int* cursor = (int*)alloc((size_t)N_NODES * 4);
  int* ssrc   = (int*)alloc((size_t)N_EDGES * 4);
  float* wts  = (float*)alloc((size_t)N_EDGES * 8 * 4);
  unsigned char* cidx = (unsigned char*)alloc((size_t)N_EDGES * 8);
  unsigned short* xb   = (unsigned short*)alloc((size_t)N_NODES * CIN * 2);
  unsigned short* hb   = (unsigned short*)alloc((size_t)N_NODES * COUT * 2);
  unsigned short* xsb  = (unsigned short*)alloc((size_t)N_NODES * CIN * 2);
  unsigned short* W1t  = (unsigned short*)alloc((size_t)COUT * KTOT * CIN * 2);
  unsigned short* W2t  = (unsigned short*)alloc((size_t)COUT * KTOT * COUT * 2);
  unsigned short* Wr1t = (unsigned short*)alloc((size_t)COUT * CIN * 2);
  unsigned short* Wr2t = (unsigned short*)alloc((size_t)COUT * COUT * 2);
  unsigned short* Wsct = (unsigned short*)alloc((size_t)COUT * CIN * 2);
  unsigned short* Wrsct= (unsigned short*)alloc((size_t)COUT * CIN * 2);
  float* msg   = (float*)alloc((size_t)N_NODES * COUT * 4);
  float* rootb = (float*)alloc((size_t)N_NODES * COUT * 4);
  float* h1    = (float*)alloc((size_t)N_NODES * COUT * 4);
  float* h2r   = (float*)alloc((size_t)N_NODES * COUT * 4);
  float* sraw  = (float*)alloc((size_t)N_NODES * COUT * 4);
  float* stats = (float*)alloc(6 * 128 * 4);
  unsigned short* accb = (unsigned short*)(base + off);
  size_t avail = (ws_size > off) ? (ws_size - off) : 0;
  size_t per_node = (size_t)KTOT * COUT * 2; // conv2 row: 32000 B
  size_t chmax = avail / per_node;
  int CH = (int)((chmax < (size_t)N_NODES) ? chmax : (size_t)N_NODES);
  if (CH < 1) CH = 1;
  const int SPLIT = 10; // 8000/10=800, 16000/10=1600 -- both multiples of 32

  hipMemsetAsync(cnt, 0, (size_t)N_NODES * 4, stream);
  hipMemsetAsync(cursor, 0, (size_t)N_NODES * 4, stream);
  hipMemsetAsync(stats, 0, 6 * 128 * 4, stream);

  count_kernel<<<CDIV(N_EDGES, 256), 256, 0, stream>>>(dst, cnt, N_EDGES);
  scan_kernel<<<1, 256, 0, stream>>>(cnt, rowptr, N_NODES);
  build_sorted<<<CDIV(N_EDGES, 256), 256, 0, stream>>>(src, dst, attr, rowptr, cursor,
                                                       ssrc, wts, cidx, N_EDGES);

  f2b_kernel<<<CDIV(N_NODES * CIN, 256), 256, 0, stream>>>(x, xb, (long)N_NODES * CIN);
  transpose_f2b<<<CDIV(KTOT * CIN * COUT, 256), 256, 0, stream>>>(W1, W1t, KTOT * CIN, COUT);
  transpose_f2b<<<CDIV(KTOT * COUT * COUT, 256), 256, 0, stream>>>(W2, W2t, KTOT * COUT, COUT);
  transpose_f2b<<<CDIV(CIN * COUT, 256), 256, 0, stream>>>(Wr1, Wr1t, CIN, COUT);
  transpose_f2b<<<CDIV(COUT * COUT, 256), 256, 0, stream>>>(Wr2, Wr2t, COUT, COUT);
  transpose_f2b<<<CDIV(CIN * COUT, 256), 256, 0, stream>>>(Wsc, Wsct, CIN, COUT);
  transpose_f2b<<<CDIV(CIN * COUT, 256), 256, 0, stream>>>(Wrsc, Wrsct, CIN, COUT);

  // ---- conv1 ----
  hipMemsetAsync(msg, 0, (size_t)N_NODES * COUT * 4, stream);
  for (int c0 = 0; c0 < N_NODES; c0 += CH) {
    int cm = (N_NODES - c0 < CH) ? (N_NODES - c0) : CH;
    scatter_kernel<<<dim3(cm, CIN / 64), 256, 0, stream>>>(xb, rowptr, ssrc, wts, cidx,
                                                           accb, c0, CIN);
    dim3 g(CDIV(cm, 128), SPLIT);
    gemm_tile<true><<<g, 256, 0, stream>>>(accb, W1t, msg + (size_t)c0 * COUT,
                                           cm, KTOT * CIN);
  }
  gemm_tile<false><<<dim3(CDIV(N_NODES, 128), 1), 256, 0, stream>>>(xb, Wr1t, rootb,
                                                                    N_NODES, CIN);
  finalize_stats<<<64, 256, 0, stream>>>(msg, rootb, b1, cnt, h1, stats, N_NODES, 1);
  bn_elu_kernel<<<CDIV(N_NODES * COUT, 256), 256, 0, stream>>>(h1, hb, stats, g1, be1, N_NODES);

  // ---- conv2 ----
  hipMemsetAsync(msg, 0, (size_t)N_NODES * COUT * 4, stream);
  for (int c0 = 0; c0 < N_NODES; c0 += CH) {
    int cm = (N_NODES - c0 < CH) ? (N_NODES - c0) : CH;
    scatter_kernel<<<dim3(cm, COUT / 64), 256, 0, stream>>>(hb, rowptr, ssrc, wts, cidx,
                                                            accb, c0, COUT);
    dim3 g(CDIV(cm, 128), SPLIT);
    gemm_tile<true><<<g, 256, 0, stream>>>(accb, W2t, msg + (size_t)c0 * COUT,
                                           cm, KTOT * COUT);
  }
  gemm_tile<false><<<dim3(CDIV(N_NODES, 128), 1), 256, 0, stream>>>(hb, Wr2t, rootb,
                                                                    N_NODES, COUT);
  finalize_stats<<<64, 256, 0, stream>>>(msg, rootb, b2, cnt, h2r, stats + 256, N_NODES, 1);

  // ---- shortcut ----
  xsum_kernel<<<N_NODES, 64, 0, stream>>>(x, rowptr, ssrc, xsb);
  gemm_tile<false><<<dim3(CDIV(N_NODES, 128), 1), 256, 0, stream>>>(xsb, Wsct, msg,
                                                                    N_NODES, CIN);
  gemm_tile<false><<<dim3(CDIV(N_NODES, 128), 1), 256, 0, stream>>>(xb, Wrsct, rootb,
                                                                    N_NODES, CIN);
  finalize_stats<<<64, 256, 0, stream>>>(msg, rootb, bsc, cnt, sraw, stats + 512, N_NODES, 0);

  // ---- output ----
  final_out_kernel<<<CDIV(N_NODES * COUT, 256), 256, 0, stream>>>(
      h2r, sraw, stats + 256, stats + 512, g2, be2, gsc, besc, out, N_NODES);
}

// Round 4
// 1185.739 us; speedup vs baseline: 3.6624x; 1.6377x over previous
//
#include <hip/hip_runtime.h>

#define N_NODES 10000
#define N_EDGES 160000
#define CIN 64
#define COUT 128
#define KTOT 125
#define NBINS (N_NODES * KTOT)          // 1,250,000
#define NPAIRS (N_EDGES * 8)            // 1,280,000
#define EPS 1e-5f

#define CDIV(a,b) (((a)+(b)-1)/(b))

typedef __attribute__((ext_vector_type(8))) short short8;
typedef __attribute__((ext_vector_type(4))) float floatx4;

static __device__ __forceinline__ unsigned short f2b(float f) {
  union { float f; unsigned u; } v; v.f = f;
  unsigned r = v.u + 0x7FFFu + ((v.u >> 16) & 1u);
  return (unsigned short)(r >> 16);
}
static __device__ __forceinline__ float b2f(unsigned short u) {
  union { unsigned u; float f; } v; v.u = ((unsigned)u) << 16;
  return v.f;
}

typedef __attribute__((address_space(1))) const unsigned int guint;
typedef __attribute__((address_space(3))) unsigned int luint;
static __device__ __forceinline__ void ld_g2l16(const void* g, void* l) {
  __builtin_amdgcn_global_load_lds((guint*)g, (luint*)l, 16, 0, 0);
}

// ---------------- CSR build (node-level: deg + dst-sorted src for xsum) --------
__global__ void count_kernel(const int* __restrict__ dst, int* __restrict__ cnt, int E) {
  int e = blockIdx.x * 256 + threadIdx.x;
  if (e < E) atomicAdd(&cnt[dst[e]], 1);
}

__global__ void scan_kernel(const int* __restrict__ cnt, int* __restrict__ rowptr, int n) {
  __shared__ int buf[256];
  __shared__ int carry;
  if (threadIdx.x == 0) { carry = 0; rowptr[0] = 0; }
  __syncthreads();
  for (int base = 0; base < n; base += 256) {
    int i = base + threadIdx.x;
    int v = (i < n) ? cnt[i] : 0;
    buf[threadIdx.x] = v;
    __syncthreads();
    for (int s = 1; s < 256; s <<= 1) {
      int t = (threadIdx.x >= s) ? buf[threadIdx.x - s] : 0;
      __syncthreads();
      buf[threadIdx.x] += t;
      __syncthreads();
    }
    if (i < n) rowptr[i + 1] = carry + buf[threadIdx.x];
    __syncthreads();
    if (threadIdx.x == 255) carry += buf[255];
    __syncthreads();
  }
}

__global__ void build_sorted(const int* __restrict__ src, const int* __restrict__ dst,
                             const int* __restrict__ rowptr, int* __restrict__ cursor,
                             int* __restrict__ ssrc, int E) {
  int e = blockIdx.x * 256 + threadIdx.x;
  if (e >= E) return;
  int d = dst[e];
  int pos = rowptr[d] + atomicAdd(&cursor[d], 1);
  ssrc[pos] = src[e];
}

// ---------------- (dst,k)-pair counting sort ----------------
static __device__ __forceinline__ void spline_corners(const float* __restrict__ attr, int e,
                                                      float* w8, int* k8) {
  float v0 = attr[e * 3 + 0] * 4.f;
  float v1 = attr[e * 3 + 1] * 4.f;
  float v2 = attr[e * 3 + 2] * 4.f;
  float b0 = floorf(v0), b1 = floorf(v1), b2 = floorf(v2);
  float f0 = v0 - b0, f1 = v1 - b1, f2 = v2 - b2;
  int i0 = (int)b0, i1 = (int)b1, i2 = (int)b2;
#pragma unroll
  for (int combo = 0; combo < 8; combo++) {
    int bit0 = combo & 1, bit1 = (combo >> 1) & 1, bit2 = (combo >> 2) & 1;
    w8[combo] = (bit0 ? f0 : 1.f - f0) * (bit1 ? f1 : 1.f - f1) * (bit2 ? f2 : 1.f - f2);
    int k0 = min(max(i0 + bit0, 0), 4);
    int k1 = min(max(i1 + bit1, 0), 4);
    int k2 = min(max(i2 + bit2, 0), 4);
    k8[combo] = k0 * 25 + k1 * 5 + k2;
  }
}

__global__ void pair_count(const int* __restrict__ dst, const float* __restrict__ attr,
                           int* __restrict__ cnt2, int E) {
  int e = blockIdx.x * 256 + threadIdx.x;
  if (e >= E) return;
  int d = dst[e];
  float w8[8]; int k8[8];
  spline_corners(attr, e, w8, k8);
#pragma unroll
  for (int c = 0; c < 8; c++) atomicAdd(&cnt2[d * KTOT + k8[c]], 1);
}

__global__ void pair_fill(const int* __restrict__ src, const int* __restrict__ dst,
                          const float* __restrict__ attr, const int* __restrict__ rowptr2,
                          int* __restrict__ cur2, int* __restrict__ psrc,
                          float* __restrict__ pw, int E) {
  int e = blockIdx.x * 256 + threadIdx.x;
  if (e >= E) return;
  int s = src[e], d = dst[e];
  float w8[8]; int k8[8];
  spline_corners(attr, e, w8, k8);
#pragma unroll
  for (int c = 0; c < 8; c++) {
    int b = d * KTOT + k8[c];
    int pos = rowptr2[b] + atomicAdd(&cur2[b], 1);
    psrc[pos] = s;
    pw[pos] = w8[c];
  }
}

// ---------------- 3-kernel exclusive scan over NBINS ints ----------------
__global__ void scan_a(const int* __restrict__ in, int* __restrict__ bsum, int n) {
  __shared__ int red[256];
  int base = blockIdx.x * 2048 + threadIdx.x * 8;
  int s = 0;
#pragma unroll
  for (int j = 0; j < 8; j++) { int i = base + j; if (i < n) s += in[i]; }
  red[threadIdx.x] = s;
  __syncthreads();
  for (int st = 128; st > 0; st >>= 1) {
    if (threadIdx.x < st) red[threadIdx.x] += red[threadIdx.x + st];
    __syncthreads();
  }
  if (threadIdx.x == 0) bsum[blockIdx.x] = red[0];
}

__global__ void scan_b(const int* __restrict__ bsum, int* __restrict__ boff, int nb,
                       int* __restrict__ rowptr2, int nbins) {
  __shared__ int buf[256];
  __shared__ int carry;
  if (threadIdx.x == 0) carry = 0;
  __syncthreads();
  for (int base = 0; base < nb; base += 256) {
    int i = base + threadIdx.x;
    int v = (i < nb) ? bsum[i] : 0;
    buf[threadIdx.x] = v;
    __syncthreads();
    for (int s = 1; s < 256; s <<= 1) {
      int t = (threadIdx.x >= s) ? buf[threadIdx.x - s] : 0;
      __syncthreads();
      buf[threadIdx.x] += t;
      __syncthreads();
    }
    if (i < nb) boff[i] = carry + buf[threadIdx.x] - v;
    __syncthreads();
    if (threadIdx.x == 255) carry += buf[255];
    __syncthreads();
  }
  if (threadIdx.x == 0) rowptr2[nbins] = carry;
}

__global__ void scan_c(const int* __restrict__ in, const int* __restrict__ boff,
                       int* __restrict__ rowptr2, int n) {
  __shared__ int buf[256];
  int base = blockIdx.x * 2048 + threadIdx.x * 8;
  int v[8], p[8];
  int s = 0;
#pragma unroll
  for (int j = 0; j < 8; j++) {
    int i = base + j;
    v[j] = (i < n) ? in[i] : 0;
    p[j] = s;
    s += v[j];
  }
  buf[threadIdx.x] = s;
  __syncthreads();
  for (int st = 1; st < 256; st <<= 1) {
    int t = (threadIdx.x >= st) ? buf[threadIdx.x - st] : 0;
    __syncthreads();
    buf[threadIdx.x] += t;
    __syncthreads();
  }
  int thr_excl = buf[threadIdx.x] - s;
  int b0 = boff[blockIdx.x];
#pragma unroll
  for (int j = 0; j < 8; j++) {
    int i = base + j;
    if (i < n) rowptr2[i] = b0 + thr_excl + p[j];
  }
}

// ---------------- converts ----------------
__global__ void f2b_kernel(const float* __restrict__ in, unsigned short* __restrict__ out, long n) {
  long i = (long)blockIdx.x * 256 + threadIdx.x;
  if (i < n) out[i] = f2b(in[i]);
}

__global__ void transpose_f2b(const float* __restrict__ in, unsigned short* __restrict__ out,
                              int K, int C) {
  long i = (long)blockIdx.x * 256 + threadIdx.x;
  long tot = (long)K * C;
  if (i >= tot) return;
  int k = (int)(i / C), c = (int)(i % C);
  out[(long)c * K + k] = f2b(in[i]);
}

// ---------------- scatter: one wave per (node,k) bin, register accumulate -------
// cin=64: lane = channel. No LDS, no atomics.
__global__ __launch_bounds__(256) void scatter_bins64(
    const unsigned short* __restrict__ Xb, const int* __restrict__ rowptr2,
    const int* __restrict__ psrc, const float* __restrict__ pw,
    unsigned short* __restrict__ accb, int bin0, int nbins_chunk) {
  int wb = blockIdx.x * 4 + (threadIdx.x >> 6);
  if (wb >= nbins_chunk) return;
  int bin = bin0 + wb;
  int lane = threadIdx.x & 63;
  int r0 = rowptr2[bin], r1 = rowptr2[bin + 1];
  float acc = 0.f;
  for (int p = r0; p < r1; p++) {
    int s = psrc[p];
    float w = pw[p];
    acc += w * b2f(Xb[(long)s * CIN + lane]);
  }
  accb[(long)wb * CIN + lane] = f2b(acc);
}

// cin=128: lane = 2 channels (packed u32 load/store).
__global__ __launch_bounds__(256) void scatter_bins128(
    const unsigned short* __restrict__ Xb, const int* __restrict__ rowptr2,
    const int* __restrict__ psrc, const float* __restrict__ pw,
    unsigned short* __restrict__ accb, int bin0, int nbins_chunk) {
  int wb = blockIdx.x * 4 + (threadIdx.x >> 6);
  if (wb >= nbins_chunk) return;
  int bin = bin0 + wb;
  int lane = threadIdx.x & 63;
  int r0 = rowptr2[bin], r1 = rowptr2[bin + 1];
  float a0 = 0.f, a1 = 0.f;
  for (int p = r0; p < r1; p++) {
    int s = psrc[p];
    float w = pw[p];
    unsigned int u = *(const unsigned int*)(Xb + (long)s * COUT + lane * 2);
    a0 += w * b2f((unsigned short)(u & 0xffffu));
    a1 += w * b2f((unsigned short)(u >> 16));
  }
  unsigned int pk = (unsigned)f2b(a0) | ((unsigned)f2b(a1) << 16);
  *(unsigned int*)(accb + (long)wb * COUT + lane * 2) = pk;
}

// ---------------- LDS-staged MFMA GEMM: C[M,128] (+)= A[M,K] * Bt[128,K]^T ----------
template<bool ATOMIC>
__global__ __launch_bounds__(256, 2) void gemm_tile(const unsigned short* __restrict__ A,
                                                    const unsigned short* __restrict__ Bt,
                                                    float* __restrict__ C, int M, int K) {
  __shared__ unsigned short As[128 * 32];
  __shared__ unsigned short Bs[128 * 32];
  int wid = threadIdx.x >> 6, lane = threadIdx.x & 63;
  int row0 = blockIdx.x * 128;
  int nslice = gridDim.y;
  int kslice = CDIV(K / 32, nslice) * 32;
  int kbeg = blockIdx.y * kslice;
  int kend = kbeg + kslice; if (kend > K) kend = K;
  if (kbeg >= K) return;

  int sub = lane & 3;
  int rload = lane >> 2;
  int q = lane >> 4, m16 = lane & 15;

  floatx4 acc[2][8];
#pragma unroll
  for (int t = 0; t < 2; t++)
#pragma unroll
    for (int c = 0; c < 8; c++) acc[t][c] = (floatx4){0.f, 0.f, 0.f, 0.f};

  for (int k0 = kbeg; k0 < kend; k0 += 32) {
    __syncthreads();
#pragma unroll
    for (int j = 0; j < 2; j++) {
      int tr = (wid * 2 + j) * 16 + rload;
      int gr = row0 + tr; if (gr >= M) gr = M - 1;
      ld_g2l16(A + (long)gr * K + k0 + sub * 8, As + (wid * 2 + j) * 512);
      ld_g2l16(Bt + (long)tr * K + k0 + sub * 8, Bs + (wid * 2 + j) * 512);
    }
    __syncthreads();
#pragma unroll
    for (int t = 0; t < 2; t++) {
      int arow = wid * 32 + t * 16 + m16;
      short8 a = *(const short8*)(As + arow * 32 + q * 8);
#pragma unroll
      for (int c = 0; c < 8; c++) {
        short8 b = *(const short8*)(Bs + (c * 16 + m16) * 32 + q * 8);
        acc[t][c] = __builtin_amdgcn_mfma_f32_16x16x32_bf16(a, b, acc[t][c], 0, 0, 0);
      }
    }
  }

#pragma unroll
  for (int t = 0; t < 2; t++) {
#pragma unroll
    for (int c = 0; c < 8; c++) {
#pragma unroll
      for (int r = 0; r < 4; r++) {
        int orow = row0 + wid * 32 + t * 16 + q * 4 + r;
        if (orow < M) {
          float* p = &C[(long)orow * COUT + c * 16 + m16];
          if (ATOMIC) atomicAdd(p, acc[t][c][r]);
          else *p = acc[t][c][r];
        }
      }
    }
  }
}

// ---------------- epilogues ----------------
__global__ void finalize_stats(const float* __restrict__ msg, const float* __restrict__ root,
                               const float* __restrict__ bias, const int* __restrict__ deg,
                               float* __restrict__ out, float* __restrict__ stats,
                               int n, int divide) {
  int c = threadIdx.x & 127;
  float bv = bias[c];
  float s = 0.f, s2 = 0.f;
  long tot = (long)n * COUT;
  long stride = (long)gridDim.x * 256;
  for (long i = (long)blockIdx.x * 256 + threadIdx.x; i < tot; i += stride) {
    int r = (int)(i >> 7);
    float mv = msg[i];
    if (divide) mv /= fmaxf((float)deg[r], 1.0f);
    float v = mv + root[i] + bv;
    out[i] = v;
    s += v; s2 += v * v;
  }
  __shared__ float ls[256], ls2[256];
  ls[threadIdx.x] = s; ls2[threadIdx.x] = s2;
  __syncthreads();
  if (threadIdx.x < 128) {
    atomicAdd(&stats[c], ls[threadIdx.x] + ls[threadIdx.x + 128]);
    atomicAdd(&stats[128 + c], ls2[threadIdx.x] + ls2[threadIdx.x + 128]);
  }
}

__global__ void bn_elu_kernel(float* __restrict__ h, unsigned short* __restrict__ hb,
                              const float* __restrict__ stats, const float* __restrict__ g,
                              const float* __restrict__ be, int n) {
  long i = (long)blockIdx.x * 256 + threadIdx.x;
  if (i >= (long)n * COUT) return;
  int c = (int)(i & 127);
  float inv_n = 1.0f / n;
  float mu = stats[c] * inv_n;
  float var = stats[128 + c] * inv_n - mu * mu;
  float v = (h[i] - mu) * rsqrtf(var + EPS) * g[c] + be[c];
  v = v > 0.f ? v : expm1f(v);
  h[i] = v;
  hb[i] = f2b(v);
}

__global__ void xsum_kernel(const float* __restrict__ x, const int* __restrict__ rowptr,
                            const int* __restrict__ ssrc, unsigned short* __restrict__ xsb) {
  int node = blockIdx.x;
  int c = threadIdx.x; // 64 threads
  int b0 = rowptr[node], b1 = rowptr[node + 1];
  float s = 0.f;
  for (int e = b0; e < b1; e++) s += x[(long)ssrc[e] * CIN + c];
  float d = (float)(b1 - b0);
  s /= fmaxf(d, 1.0f);
  xsb[(long)node * CIN + c] = f2b(s);
}

__global__ void final_out_kernel(const float* __restrict__ h2, const float* __restrict__ sraw,
                                 const float* __restrict__ st2, const float* __restrict__ stsc,
                                 const float* __restrict__ g2, const float* __restrict__ be2,
                                 const float* __restrict__ gsc, const float* __restrict__ besc,
                                 float* __restrict__ out, int n) {
  long i = (long)blockIdx.x * 256 + threadIdx.x;
  if (i >= (long)n * COUT) return;
  int c = (int)(i & 127);
  float inv_n = 1.0f / n;
  float mu2 = st2[c] * inv_n;
  float var2 = st2[128 + c] * inv_n - mu2 * mu2;
  float a = (h2[i] - mu2) * rsqrtf(var2 + EPS) * g2[c] + be2[c];
  float musc = stsc[c] * inv_n;
  float varsc = stsc[128 + c] * inv_n - musc * musc;
  float b = (sraw[i] - musc) * rsqrtf(varsc + EPS) * gsc[c] + besc[c];
  float v = a + b;
  out[i] = v > 0.f ? v : expm1f(v);
}

// ---------------- host ----------------
extern "C" void kernel_launch(void* const* d_in, const int* in_sizes, int n_in,
                              void* d_out, int out_size, void* d_ws, size_t ws_size,
                              hipStream_t stream) {
  const float* x    = (const float*)d_in[0];
  const int*   eidx = (const int*)d_in[1];
  const float* attr = (const float*)d_in[2];
  const float* W1   = (const float*)d_in[3];
  const float* Wr1  = (const float*)d_in[4];
  const float* b1   = (const float*)d_in[5];
  const float* g1   = (const float*)d_in[6];
  const float* be1  = (const float*)d_in[7];
  const float* W2   = (const float*)d_in[8];
  const float* Wr2  = (const float*)d_in[9];
  const float* b2   = (const float*)d_in[10];
  const float* g2   = (const float*)d_in[11];
  const float* be2  = (const float*)d_in[12];
  const float* Wsc  = (const float*)d_in[13];
  const float* Wrsc = (const float*)d_in[14];
  const float* bsc  = (const float*)d_in[15];
  const float* gsc  = (const float*)d_in[16];
  const float* besc = (const float*)d_in[17];
  float* out = (float*)d_out;

  const int* src = eidx;
  const int* dst = eidx + N_EDGES;

  char* base = (char*)d_ws;
  size_t off = 0;
  auto alloc = [&](size_t bytes) -> char* {
    char* p = base + off;
    off += (bytes + 255) & ~(size_t)255;
    return p;
  };
  int* cnt    = (int*)alloc((size_t)N_NODES * 4);
  int* rowptr = (int*)alloc((size_t)(N_NODES + 1) * 4);
  int* cursor = (int*)alloc((size_t)N_NODES * 4);
  int* ssrc   = (int*)alloc((size_t)N_EDGES * 4);
  int* cnt2   = (int*)alloc((size_t)NBINS * 4);
  int* cur2   = (int*)alloc((size_t)NBINS * 4);
  int* rowptr2= (int*)alloc((size_t)(NBINS + 1) * 4);
  const int NB_SCAN = CDIV(NBINS, 2048);
  int* bsum   = (int*)alloc((size_t)(NB_SCAN + 1) * 4);
  int* boff   = (int*)alloc((size_t)(NB_SCAN + 1) * 4);
  int* psrc   = (int*)alloc((size_t)NPAIRS * 4);
  float* pw   = (float*)alloc((size_t)NPAIRS * 4);
  unsigned short* xb   = (unsigned short*)alloc((size_t)N_NODES * CIN * 2);
  unsigned short* hb   = (unsigned short*)alloc((size_t)N_NODES * COUT * 2);
  unsigned short* xsb  = (unsigned short*)alloc((size_t)N_NODES * CIN * 2);
  unsigned short* W1t  = (unsigned short*)alloc((size_t)COUT * KTOT * CIN * 2);
  unsigned short* W2t  = (unsigned short*)alloc((size_t)COUT * KTOT * COUT * 2);
  unsigned short* Wr1t = (unsigned short*)alloc((size_t)COUT * CIN * 2);
  unsigned short* Wr2t = (unsigned short*)alloc((size_t)COUT * COUT * 2);
  unsigned short* Wsct = (unsigned short*)alloc((size_t)COUT * CIN * 2);
  unsigned short* Wrsct= (unsigned short*)alloc((size_t)COUT * CIN * 2);
  float* msg   = (float*)alloc((size_t)N_NODES * COUT * 4);
  float* rootb = (float*)alloc((size_t)N_NODES * COUT * 4);
  float* h1    = (float*)alloc((size_t)N_NODES * COUT * 4);
  float* h2r   = (float*)alloc((size_t)N_NODES * COUT * 4);
  float* sraw  = (float*)alloc((size_t)N_NODES * COUT * 4);
  float* stats = (float*)alloc(6 * 128 * 4);
  unsigned short* accb = (unsigned short*)(base + off);
  size_t avail = (ws_size > off) ? (ws_size - off) : 0;
  size_t per_node = (size_t)KTOT * COUT * 2; // conv2 row: 32000 B
  size_t chmax = avail / per_node;
  int CH = (int)((chmax < (size_t)N_NODES) ? chmax : (size_t)N_NODES);
  if (CH < 1) CH = 1;
  const int SPLIT = 10;

  hipMemsetAsync(cnt, 0, (size_t)N_NODES * 4, stream);
  hipMemsetAsync(cursor, 0, (size_t)N_NODES * 4, stream);
  hipMemsetAsync(cnt2, 0, (size_t)NBINS * 4, stream);
  hipMemsetAsync(cur2, 0, (size_t)NBINS * 4, stream);
  hipMemsetAsync(stats, 0, 6 * 128 * 4, stream);

  // node-level CSR (deg + sorted src) for mean + shortcut
  count_kernel<<<CDIV(N_EDGES, 256), 256, 0, stream>>>(dst, cnt, N_EDGES);
  scan_kernel<<<1, 256, 0, stream>>>(cnt, rowptr, N_NODES);
  build_sorted<<<CDIV(N_EDGES, 256), 256, 0, stream>>>(src, dst, rowptr, cursor, ssrc, N_EDGES);

  // (dst,k)-pair counting sort
  pair_count<<<CDIV(N_EDGES, 256), 256, 0, stream>>>(dst, attr, cnt2, N_EDGES);
  scan_a<<<NB_SCAN, 256, 0, stream>>>(cnt2, bsum, NBINS);
  scan_b<<<1, 256, 0, stream>>>(bsum, boff, NB_SCAN, rowptr2, NBINS);
  scan_c<<<NB_SCAN, 256, 0, stream>>>(cnt2, boff, rowptr2, NBINS);
  pair_fill<<<CDIV(N_EDGES, 256), 256, 0, stream>>>(src, dst, attr, rowptr2, cur2,
                                                    psrc, pw, N_EDGES);

  f2b_kernel<<<CDIV(N_NODES * CIN, 256), 256, 0, stream>>>(x, xb, (long)N_NODES * CIN);
  transpose_f2b<<<CDIV(KTOT * CIN * COUT, 256), 256, 0, stream>>>(W1, W1t, KTOT * CIN, COUT);
  transpose_f2b<<<CDIV(KTOT * COUT * COUT, 256), 256, 0, stream>>>(W2, W2t, KTOT * COUT, COUT);
  transpose_f2b<<<CDIV(CIN * COUT, 256), 256, 0, stream>>>(Wr1, Wr1t, CIN, COUT);
  transpose_f2b<<<CDIV(COUT * COUT, 256), 256, 0, stream>>>(Wr2, Wr2t, COUT, COUT);
  transpose_f2b<<<CDIV(CIN * COUT, 256), 256, 0, stream>>>(Wsc, Wsct, CIN, COUT);
  transpose_f2b<<<CDIV(CIN * COUT, 256), 256, 0, stream>>>(Wrsc, Wrsct, CIN, COUT);

  // ---- conv1 ----
  hipMemsetAsync(msg, 0, (size_t)N_NODES * COUT * 4, stream);
  for (int c0 = 0; c0 < N_NODES; c0 += CH) {
    int cm = (N_NODES - c0 < CH) ? (N_NODES - c0) : CH;
    int nbc = cm * KTOT;
    scatter_bins64<<<CDIV(nbc, 4), 256, 0, stream>>>(xb, rowptr2, psrc, pw, accb,
                                                     c0 * KTOT, nbc);
    dim3 g(CDIV(cm, 128), SPLIT);
    gemm_tile<true><<<g, 256, 0, stream>>>(accb, W1t, msg + (size_t)c0 * COUT,
                                           cm, KTOT * CIN);
  }
  gemm_tile<false><<<dim3(CDIV(N_NODES, 128), 1), 256, 0, stream>>>(xb, Wr1t, rootb,
                                                                    N_NODES, CIN);
  finalize_stats<<<64, 256, 0, stream>>>(msg, rootb, b1, cnt, h1, stats, N_NODES, 1);
  bn_elu_kernel<<<CDIV(N_NODES * COUT, 256), 256, 0, stream>>>(h1, hb, stats, g1, be1, N_NODES);

  // ---- conv2 ----
  hipMemsetAsync(msg, 0, (size_t)N_NODES * COUT * 4, stream);
  for (int c0 = 0; c0 < N_NODES; c0 += CH) {
    int cm = (N_NODES - c0 < CH) ? (N_NODES - c0) : CH;
    int nbc = cm * KTOT;
    scatter_bins128<<<CDIV(nbc, 4), 256, 0, stream>>>(hb, rowptr2, psrc, pw, accb,
                                                      c0 * KTOT, nbc);
    dim3 g(CDIV(cm, 128), SPLIT);
    gemm_tile<true><<<g, 256, 0, stream>>>(accb, W2t, msg + (size_t)c0 * COUT,
                                           cm, KTOT * COUT);
  }
  gemm_tile<false><<<dim3(CDIV(N_NODES, 128), 1), 256, 0, stream>>>(hb, Wr2t, rootb,
                                                                    N_NODES, COUT);
  finalize_stats<<<64, 256, 0, stream>>>(msg, rootb, b2, cnt, h2r, stats + 256, N_NODES, 1);

  // ---- shortcut ----
  xsum_kernel<<<N_NODES, 64, 0, stream>>>(x, rowptr, ssrc, xsb);
  gemm_tile<false><<<dim3(CDIV(N_NODES, 128), 1), 256, 0, stream>>>(xsb, Wsct, msg,
                                                                    N_NODES, CIN);
  gemm_tile<false><<<dim3(CDIV(N_NODES, 128), 1), 256, 0, stream>>>(xb, Wrsct, rootb,
                                                                    N_NODES, CIN);
  finalize_stats<<<64, 256, 0, stream>>>(msg, rootb, bsc, cnt, sraw, stats + 512, N_NODES, 0);

  // ---- output ----
  final_out_kernel<<<CDIV(N_NODES * COUT, 256), 256, 0, stream>>>(
      h2r, sraw, stats + 256, stats + 512, g2, be2, gsc, besc, out, N_NODES);
}

// Round 5
// 911.561 us; speedup vs baseline: 4.7639x; 1.3008x over previous
//
#include <hip/hip_runtime.h>

#define N_NODES 10000
#define N_EDGES 160000
#define CIN 64
#define COUT 128
#define KTOT 125
#define NBINS (N_NODES * KTOT)          // 1,250,000
#define NPAIRS (N_EDGES * 8)            // 1,280,000
#define EPS 1e-5f

#define CDIV(a,b) (((a)+(b)-1)/(b))

typedef __attribute__((ext_vector_type(8))) short short8;
typedef __attribute__((ext_vector_type(4))) float floatx4;

static __device__ __forceinline__ unsigned short f2b(float f) {
  union { float f; unsigned u; } v; v.f = f;
  unsigned r = v.u + 0x7FFFu + ((v.u >> 16) & 1u);
  return (unsigned short)(r >> 16);
}
static __device__ __forceinline__ float b2f(unsigned short u) {
  union { unsigned u; float f; } v; v.u = ((unsigned)u) << 16;
  return v.f;
}

typedef __attribute__((address_space(1))) const unsigned int guint;
typedef __attribute__((address_space(3))) unsigned int luint;
static __device__ __forceinline__ void ld_g2l16(const void* g, void* l) {
  __builtin_amdgcn_global_load_lds((guint*)g, (luint*)l, 16, 0, 0);
}

// ---------------- (dst,k)-pair counting sort ----------------
static __device__ __forceinline__ void spline_corners(const float* __restrict__ attr, int e,
                                                      float* w8, int* k8) {
  float v0 = attr[e * 3 + 0] * 4.f;
  float v1 = attr[e * 3 + 1] * 4.f;
  float v2 = attr[e * 3 + 2] * 4.f;
  float b0 = floorf(v0), b1 = floorf(v1), b2 = floorf(v2);
  float f0 = v0 - b0, f1 = v1 - b1, f2 = v2 - b2;
  int i0 = (int)b0, i1 = (int)b1, i2 = (int)b2;
#pragma unroll
  for (int combo = 0; combo < 8; combo++) {
    int bit0 = combo & 1, bit1 = (combo >> 1) & 1, bit2 = (combo >> 2) & 1;
    w8[combo] = (bit0 ? f0 : 1.f - f0) * (bit1 ? f1 : 1.f - f1) * (bit2 ? f2 : 1.f - f2);
    int k0 = min(max(i0 + bit0, 0), 4);
    int k1 = min(max(i1 + bit1, 0), 4);
    int k2 = min(max(i2 + bit2, 0), 4);
    k8[combo] = k0 * 25 + k1 * 5 + k2;
  }
}

__global__ void pair_count(const int* __restrict__ dst, const float* __restrict__ attr,
                           int* __restrict__ cnt2, int E) {
  int e = blockIdx.x * 256 + threadIdx.x;
  if (e >= E) return;
  int d = dst[e];
  float w8[8]; int k8[8];
  spline_corners(attr, e, w8, k8);
#pragma unroll
  for (int c = 0; c < 8; c++) atomicAdd(&cnt2[d * KTOT + k8[c]], 1);
}

// cur2 pre-seeded with rowptr2 values by scan_c -> atomicAdd gives absolute slot
__global__ void pair_fill(const int* __restrict__ src, const int* __restrict__ dst,
                          const float* __restrict__ attr, int* __restrict__ cur2,
                          int* __restrict__ psrc, float* __restrict__ pw, int E) {
  int e = blockIdx.x * 256 + threadIdx.x;
  if (e >= E) return;
  int s = src[e], d = dst[e];
  float w8[8]; int k8[8];
  spline_corners(attr, e, w8, k8);
#pragma unroll
  for (int c = 0; c < 8; c++) {
    int b = d * KTOT + k8[c];
    int pos = atomicAdd(&cur2[b], 1);
    psrc[pos] = s;
    pw[pos] = w8[c];
  }
}

// ---------------- 3-kernel exclusive scan over NBINS ints ----------------
__global__ void scan_a(const int* __restrict__ in, int* __restrict__ bsum, int n) {
  __shared__ int red[256];
  int base = blockIdx.x * 2048 + threadIdx.x * 8;
  int s = 0;
#pragma unroll
  for (int j = 0; j < 8; j++) { int i = base + j; if (i < n) s += in[i]; }
  red[threadIdx.x] = s;
  __syncthreads();
  for (int st = 128; st > 0; st >>= 1) {
    if (threadIdx.x < st) red[threadIdx.x] += red[threadIdx.x + st];
    __syncthreads();
  }
  if (threadIdx.x == 0) bsum[blockIdx.x] = red[0];
}

// also zeroes the stats block (piggyback; must run before any finalize kernel)
__global__ void scan_b(const int* __restrict__ bsum, int* __restrict__ boff, int nb,
                       int* __restrict__ rowptr2, int nbins, float* __restrict__ stats) {
  for (int i = threadIdx.x; i < 6 * 128; i += 256) stats[i] = 0.f;
  __shared__ int buf[256];
  __shared__ int carry;
  if (threadIdx.x == 0) carry = 0;
  __syncthreads();
  for (int base = 0; base < nb; base += 256) {
    int i = base + threadIdx.x;
    int v = (i < nb) ? bsum[i] : 0;
    buf[threadIdx.x] = v;
    __syncthreads();
    for (int s = 1; s < 256; s <<= 1) {
      int t = (threadIdx.x >= s) ? buf[threadIdx.x - s] : 0;
      __syncthreads();
      buf[threadIdx.x] += t;
      __syncthreads();
    }
    if (i < nb) boff[i] = carry + buf[threadIdx.x] - v;
    __syncthreads();
    if (threadIdx.x == 255) carry += buf[255];
    __syncthreads();
  }
  if (threadIdx.x == 0) rowptr2[nbins] = carry;
}

// writes rowptr2[i] and seeds cur2[i] with the same value
__global__ void scan_c(const int* __restrict__ in, const int* __restrict__ boff,
                       int* __restrict__ rowptr2, int* __restrict__ cur2, int n) {
  __shared__ int buf[256];
  int base = blockIdx.x * 2048 + threadIdx.x * 8;
  int v[8], p[8];
  int s = 0;
#pragma unroll
  for (int j = 0; j < 8; j++) {
    int i = base + j;
    v[j] = (i < n) ? in[i] : 0;
    p[j] = s;
    s += v[j];
  }
  buf[threadIdx.x] = s;
  __syncthreads();
  for (int st = 1; st < 256; st <<= 1) {
    int t = (threadIdx.x >= st) ? buf[threadIdx.x - st] : 0;
    __syncthreads();
    buf[threadIdx.x] += t;
    __syncthreads();
  }
  int thr_excl = buf[threadIdx.x] - s;
  int b0 = boff[blockIdx.x];
#pragma unroll
  for (int j = 0; j < 8; j++) {
    int i = base + j;
    if (i < n) { int val = b0 + thr_excl + p[j]; rowptr2[i] = val; cur2[i] = val; }
  }
}

// ---------------- one-shot convert: xb + all weight transposes ----------------
// segments (output elem counts): xb 640000 | W1t 1024000 | W2t 2048000 |
// rootBt(Wr1) 8192 | rootBt(Wrsc) 8192 | Wr2t 16384 | Wsct 8192
__global__ void convert_all(const float* __restrict__ x, const float* __restrict__ W1,
                            const float* __restrict__ W2, const float* __restrict__ Wr1,
                            const float* __restrict__ Wrsc, const float* __restrict__ Wr2,
                            const float* __restrict__ Wsc,
                            unsigned short* __restrict__ xb, unsigned short* __restrict__ W1t,
                            unsigned short* __restrict__ W2t, unsigned short* __restrict__ rootBt,
                            unsigned short* __restrict__ Wr2t, unsigned short* __restrict__ Wsct) {
  long i = (long)blockIdx.x * 256 + threadIdx.x;
  const long n0 = 640000, n1 = n0 + 1024000, n2 = n1 + 2048000,
             n3 = n2 + 8192, n4 = n3 + 8192, n5 = n4 + 16384, n6 = n5 + 8192;
  if (i < n0) {
    xb[i] = f2b(x[i]);
  } else if (i < n1) {
    long j = i - n0; int k = (int)(j >> 7), c = (int)(j & 127);
    W1t[(long)c * 8000 + k] = f2b(W1[j]);
  } else if (i < n2) {
    long j = i - n1; int k = (int)(j >> 7), c = (int)(j & 127);
    W2t[(long)c * 16000 + k] = f2b(W2[j]);
  } else if (i < n3) {
    long j = i - n2; int k = (int)(j >> 7), c = (int)(j & 127);
    rootBt[c * 64 + k] = f2b(Wr1[j]);
  } else if (i < n4) {
    long j = i - n3; int k = (int)(j >> 7), c = (int)(j & 127);
    rootBt[(128 + c) * 64 + k] = f2b(Wrsc[j]);
  } else if (i < n5) {
    long j = i - n4; int k = (int)(j >> 7), c = (int)(j & 127);
    Wr2t[c * 128 + k] = f2b(Wr2[j]);
  } else if (i < n6) {
    long j = i - n5; int k = (int)(j >> 7), c = (int)(j & 127);
    Wsct[c * 64 + k] = f2b(Wsc[j]);
  }
}

// ---------------- scatter: one wave per 8 consecutive bins, register accumulate --
template<int C>
__global__ __launch_bounds__(256) void scatter_bins(
    const unsigned short* __restrict__ Xb, const int* __restrict__ rowptr2,
    const int* __restrict__ psrc, const float* __restrict__ pw,
    unsigned short* __restrict__ accb, int bin0, int nbins_chunk) {
  int wb0 = (blockIdx.x * 4 + (threadIdx.x >> 6)) * 8;
  if (wb0 >= nbins_chunk) return;
  int lane = threadIdx.x & 63;
  int bin = bin0 + wb0;
  int bounds = 0;
  if (lane < 9) bounds = rowptr2[bin + lane];
  int b[9];
#pragma unroll
  for (int j = 0; j < 9; j++) b[j] = __shfl(bounds, j, 64);
#pragma unroll
  for (int j = 0; j < 8; j++) {
    int wb = wb0 + j;
    if (wb >= nbins_chunk) break;
    float a0 = 0.f, a1 = 0.f;
    for (int p = b[j]; p < b[j + 1]; p++) {
      int s = psrc[p];
      float w = pw[p];
      if (C == 64) {
        a0 += w * b2f(Xb[(long)s * 64 + lane]);
      } else {
        unsigned u = *(const unsigned*)(Xb + (long)s * 128 + lane * 2);
        a0 += w * b2f((unsigned short)(u & 0xffffu));
        a1 += w * b2f((unsigned short)(u >> 16));
      }
    }
    if (C == 64) {
      accb[(long)wb * 64 + lane] = f2b(a0);
    } else {
      unsigned pk = (unsigned)f2b(a0) | ((unsigned)f2b(a1) << 16);
      *(unsigned*)(accb + (long)wb * 128 + lane * 2) = pk;
    }
  }
}

// ---------------- LDS-staged MFMA GEMM ----------------
// C[M, NCOLS] (+)= A[M,K] * Bt[NCOLS,K]^T ; 128x128 tile, col-block = blockIdx.z.
template<int NCOLS, bool ATOMIC>
__global__ __launch_bounds__(256, 2) void gemm_tile(const unsigned short* __restrict__ A,
                                                    const unsigned short* __restrict__ Bt,
                                                    float* __restrict__ C, int M, int K) {
  __shared__ unsigned short As[128 * 32];
  __shared__ unsigned short Bs[128 * 32];
  int wid = threadIdx.x >> 6, lane = threadIdx.x & 63;
  int row0 = blockIdx.x * 128;
  int cb = blockIdx.z * 128;
  int nslice = gridDim.y;
  int kslice = CDIV(K / 32, nslice) * 32;
  int kbeg = blockIdx.y * kslice;
  int kend = kbeg + kslice; if (kend > K) kend = K;
  if (kbeg >= K) return;

  int sub = lane & 3;
  int rload = lane >> 2;
  int q = lane >> 4, m16 = lane & 15;

  floatx4 acc[2][8];
#pragma unroll
  for (int t = 0; t < 2; t++)
#pragma unroll
    for (int c = 0; c < 8; c++) acc[t][c] = (floatx4){0.f, 0.f, 0.f, 0.f};

  for (int k0 = kbeg; k0 < kend; k0 += 32) {
    __syncthreads();
#pragma unroll
    for (int j = 0; j < 2; j++) {
      int tr = (wid * 2 + j) * 16 + rload;
      int gr = row0 + tr; if (gr >= M) gr = M - 1;
      ld_g2l16(A + (long)gr * K + k0 + sub * 8, As + (wid * 2 + j) * 512);
      ld_g2l16(Bt + (long)(cb + tr) * K + k0 + sub * 8, Bs + (wid * 2 + j) * 512);
    }
    __syncthreads();
#pragma unroll
    for (int t = 0; t < 2; t++) {
      int arow = wid * 32 + t * 16 + m16;
      short8 a = *(const short8*)(As + arow * 32 + q * 8);
#pragma unroll
      for (int c = 0; c < 8; c++) {
        short8 b = *(const short8*)(Bs + (c * 16 + m16) * 32 + q * 8);
        acc[t][c] = __builtin_amdgcn_mfma_f32_16x16x32_bf16(a, b, acc[t][c], 0, 0, 0);
      }
    }
  }

#pragma unroll
  for (int t = 0; t < 2; t++) {
#pragma unroll
    for (int c = 0; c < 8; c++) {
#pragma unroll
      for (int r = 0; r < 4; r++) {
        int orow = row0 + wid * 32 + t * 16 + q * 4 + r;
        if (orow < M) {
          float* p = &C[(long)orow * NCOLS + cb + c * 16 + m16];
          if (ATOMIC) atomicAdd(p, acc[t][c][r]);
          else *p = acc[t][c][r];
        }
      }
    }
  }
}

// ---------------- epilogues ----------------
// deg(n) derived from pair CSR: each edge contributes exactly 8 pairs.
static __device__ __forceinline__ float node_deg(const int* __restrict__ rowptr2, int r) {
  return (float)((rowptr2[(r + 1) * KTOT] - rowptr2[r * KTOT]) >> 3);
}

__global__ void finalize_stats(const float* __restrict__ msg, const float* __restrict__ root,
                               int rstride, int roff, const float* __restrict__ bias,
                               const int* __restrict__ rowptr2,
                               float* __restrict__ out, float* __restrict__ stats, int n) {
  int c = threadIdx.x & 127;
  float bv = bias[c];
  float s = 0.f, s2 = 0.f;
  long tot = (long)n * COUT;
  long stride = (long)gridDim.x * 256;
  for (long i = (long)blockIdx.x * 256 + threadIdx.x; i < tot; i += stride) {
    int r = (int)(i >> 7);
    float v = msg[i] / fmaxf(node_deg(rowptr2, r), 1.0f)
            + root[(long)r * rstride + roff + c] + bv;
    out[i] = v;
    s += v; s2 += v * v;
  }
  __shared__ float ls[256], ls2[256];
  ls[threadIdx.x] = s; ls2[threadIdx.x] = s2;
  __syncthreads();
  if (threadIdx.x < 128) {
    atomicAdd(&stats[c], ls[threadIdx.x] + ls[threadIdx.x + 128]);
    atomicAdd(&stats[128 + c], ls2[threadIdx.x] + ls2[threadIdx.x + 128]);
  }
}

// fused finalize for conv2 (with mean) + shortcut (no mean), two stat sets
__global__ void finalize2_dual(const float* __restrict__ msg2, const float* __restrict__ rootb2,
                               const float* __restrict__ b2, const float* __restrict__ msgsc,
                               const float* __restrict__ rootb, const float* __restrict__ bsc,
                               const int* __restrict__ rowptr2, float* __restrict__ h2r,
                               float* __restrict__ sraw, float* __restrict__ stats2,
                               float* __restrict__ statssc, int n) {
  int c = threadIdx.x & 127;
  float bv2 = b2[c], bvsc = bsc[c];
  float sa = 0.f, sb = 0.f, ta = 0.f, tb = 0.f;
  long tot = (long)n * COUT;
  long stride = (long)gridDim.x * 256;
  for (long i = (long)blockIdx.x * 256 + threadIdx.x; i < tot; i += stride) {
    int r = (int)(i >> 7);
    float v2 = msg2[i] / fmaxf(node_deg(rowptr2, r), 1.0f) + rootb2[i] + bv2;
    h2r[i] = v2;
    sa += v2; sb += v2 * v2;
    float vs = msgsc[i] + rootb[(long)r * 256 + 128 + c] + bvsc;
    sraw[i] = vs;
    ta += vs; tb += vs * vs;
  }
  __shared__ float l0[256], l1[256], l2[256], l3[256];
  l0[threadIdx.x] = sa; l1[threadIdx.x] = sb; l2[threadIdx.x] = ta; l3[threadIdx.x] = tb;
  __syncthreads();
  if (threadIdx.x < 128) {
    atomicAdd(&stats2[c], l0[threadIdx.x] + l0[threadIdx.x + 128]);
    atomicAdd(&stats2[128 + c], l1[threadIdx.x] + l1[threadIdx.x + 128]);
    atomicAdd(&statssc[c], l2[threadIdx.x] + l2[threadIdx.x + 128]);
    atomicAdd(&statssc[128 + c], l3[threadIdx.x] + l3[threadIdx.x + 128]);
  }
}

__global__ void bn_elu_kernel(float* __restrict__ h, unsigned short* __restrict__ hb,
                              const float* __restrict__ stats, const float* __restrict__ g,
                              const float* __restrict__ be, int n) {
  long i = (long)blockIdx.x * 256 + threadIdx.x;
  if (i >= (long)n * COUT) return;
  int c = (int)(i & 127);
  float inv_n = 1.0f / n;
  float mu = stats[c] * inv_n;
  float var = stats[128 + c] * inv_n - mu * mu;
  float v = (h[i] - mu) * rsqrtf(var + EPS) * g[c] + be[c];
  v = v > 0.f ? v : expm1f(v);
  h[i] = v;
  hb[i] = f2b(v);
}

// shortcut mean input: since sum_c w_c = 1 per edge, sum over a node's pair range
// of w*x[src] == sum over its edges of x[src]. 4 nodes per block.
__global__ void xsum_pairs(const unsigned short* __restrict__ xb,
                           const int* __restrict__ rowptr2, const int* __restrict__ psrc,
                           const float* __restrict__ pw, unsigned short* __restrict__ xsb) {
  int node = blockIdx.x * 4 + (threadIdx.x >> 6);
  if (node >= N_NODES) return;
  int lane = threadIdx.x & 63;
  int r0 = rowptr2[node * KTOT], r1 = rowptr2[(node + 1) * KTOT];
  float s = 0.f;
  for (int p = r0; p < r1; p++)
    s += pw[p] * b2f(xb[(long)psrc[p] * CIN + lane]);
  float d = (float)((r1 - r0) >> 3);
  s /= fmaxf(d, 1.0f);
  xsb[(long)node * CIN + lane] = f2b(s);
}

__global__ void final_out_kernel(const float* __restrict__ h2, const float* __restrict__ sraw,
                                 const float* __restrict__ st2, const float* __restrict__ stsc,
                                 const float* __restrict__ g2, const float* __restrict__ be2,
                                 const float* __restrict__ gsc, const float* __restrict__ besc,
                                 float* __restrict__ out, int n) {
  long i = (long)blockIdx.x * 256 + threadIdx.x;
  if (i >= (long)n * COUT) return;
  int c = (int)(i & 127);
  float inv_n = 1.0f / n;
  float mu2 = st2[c] * inv_n;
  float var2 = st2[128 + c] * inv_n - mu2 * mu2;
  float a = (h2[i] - mu2) * rsqrtf(var2 + EPS) * g2[c] + be2[c];
  float musc = stsc[c] * inv_n;
  float varsc = stsc[128 + c] * inv_n - musc * musc;
  float b = (sraw[i] - musc) * rsqrtf(varsc + EPS) * gsc[c] + besc[c];
  float v = a + b;
  out[i] = v > 0.f ? v : expm1f(v);
}

// ---------------- host ----------------
extern "C" void kernel_launch(void* const* d_in, const int* in_sizes, int n_in,
                              void* d_out, int out_size, void* d_ws, size_t ws_size,
                              hipStream_t stream) {
  const float* x    = (const float*)d_in[0];
  const int*   eidx = (const int*)d_in[1];
  const float* attr = (const float*)d_in[2];
  const float* W1   = (const float*)d_in[3];
  const float* Wr1  = (const float*)d_in[4];
  const float* b1   = (const float*)d_in[5];
  const float* g1   = (const float*)d_in[6];
  const float* be1  = (const float*)d_in[7];
  const float* W2   = (const float*)d_in[8];
  const float* Wr2  = (const float*)d_in[9];
  const float* b2   = (const float*)d_in[10];
  const float* g2   = (const float*)d_in[11];
  const float* be2  = (const float*)d_in[12];
  const float* Wsc  = (const float*)d_in[13];
  const float* Wrsc = (const float*)d_in[14];
  const float* bsc  = (const float*)d_in[15];
  const float* gsc  = (const float*)d_in[16];
  const float* besc = (const float*)d_in[17];
  float* out = (float*)d_out;

  const int* src = eidx;
  const int* dst = eidx + N_EDGES;

  char* base = (char*)d_ws;
  size_t off = 0;
  auto alloc = [&](size_t bytes) -> char* {
    char* p = base + off;
    off += (bytes + 255) & ~(size_t)255;
    return p;
  };
  int* cnt2   = (int*)alloc((size_t)NBINS * 4);
  int* cur2   = (int*)alloc((size_t)NBINS * 4);
  int* rowptr2= (int*)alloc((size_t)(NBINS + 1) * 4);
  const int NB_SCAN = CDIV(NBINS, 2048);
  int* bsum   = (int*)alloc((size_t)(NB_SCAN + 1) * 4);
  int* boff   = (int*)alloc((size_t)(NB_SCAN + 1) * 4);
  int* psrc   = (int*)alloc((size_t)NPAIRS * 4);
  float* pw   = (float*)alloc((size_t)NPAIRS * 4);
  unsigned short* xb    = (unsigned short*)alloc((size_t)N_NODES * CIN * 2);
  unsigned short* hb    = (unsigned short*)alloc((size_t)N_NODES * COUT * 2);
  unsigned short* xsb   = (unsigned short*)alloc((size_t)N_NODES * CIN * 2);
  unsigned short* W1t   = (unsigned short*)alloc((size_t)COUT * KTOT * CIN * 2);
  unsigned short* W2t   = (unsigned short*)alloc((size_t)COUT * KTOT * COUT * 2);
  unsigned short* rootBt= (unsigned short*)alloc((size_t)256 * CIN * 2);
  unsigned short* Wr2t  = (unsigned short*)alloc((size_t)COUT * COUT * 2);
  unsigned short* Wsct  = (unsigned short*)alloc((size_t)COUT * CIN * 2);
  float* msg   = (float*)alloc((size_t)N_NODES * COUT * 4);   // conv1 (zeroed)
  float* msg2  = (float*)alloc((size_t)N_NODES * COUT * 4);   // conv2 (zeroed, adjacent)
  float* msgsc = (float*)alloc((size_t)N_NODES * COUT * 4);
  float* rootb = (float*)alloc((size_t)N_NODES * 256 * 4);    // [Wr1 | Wrsc] outputs
  float* rootb2= (float*)alloc((size_t)N_NODES * COUT * 4);
  float* h1    = (float*)alloc((size_t)N_NODES * COUT * 4);
  float* h2r   = (float*)alloc((size_t)N_NODES * COUT * 4);
  float* sraw  = (float*)alloc((size_t)N_NODES * COUT * 4);
  float* stats = (float*)alloc(6 * 128 * 4);
  unsigned short* accb = (unsigned short*)(base + off);
  size_t avail = (ws_size > off) ? (ws_size - off) : 0;
  size_t per_node = (size_t)KTOT * COUT * 2;
  size_t chmax = avail / per_node;
  int CH = (int)((chmax < (size_t)N_NODES) ? chmax : (size_t)N_NODES);
  if (CH < 1) CH = 1;
  const int SPLIT = 10;

  hipMemsetAsync(cnt2, 0, (size_t)NBINS * 4, stream);
  hipMemsetAsync(msg, 0, (size_t)N_NODES * COUT * 8, stream);  // msg + msg2

  // (dst,k)-pair counting sort (stats zeroed in scan_b, cur2 seeded in scan_c)
  pair_count<<<CDIV(N_EDGES, 256), 256, 0, stream>>>(dst, attr, cnt2, N_EDGES);
  scan_a<<<NB_SCAN, 256, 0, stream>>>(cnt2, bsum, NBINS);
  scan_b<<<1, 256, 0, stream>>>(bsum, boff, NB_SCAN, rowptr2, NBINS, stats);
  scan_c<<<NB_SCAN, 256, 0, stream>>>(cnt2, boff, rowptr2, cur2, NBINS);
  pair_fill<<<CDIV(N_EDGES, 256), 256, 0, stream>>>(src, dst, attr, cur2, psrc, pw, N_EDGES);

  const long CONV_TOT = 640000L + 1024000L + 2048000L + 8192 + 8192 + 16384 + 8192;
  convert_all<<<CDIV(CONV_TOT, 256), 256, 0, stream>>>(x, W1, W2, Wr1, Wrsc, Wr2, Wsc,
                                                       xb, W1t, W2t, rootBt, Wr2t, Wsct);
  xsum_pairs<<<CDIV(N_NODES, 4), 256, 0, stream>>>(xb, rowptr2, psrc, pw, xsb);

  // ---- conv1 ----
  for (int c0 = 0; c0 < N_NODES; c0 += CH) {
    int cm = (N_NODES - c0 < CH) ? (N_NODES - c0) : CH;
    int nbc = cm * KTOT;
    scatter_bins<64><<<CDIV(nbc, 32), 256, 0, stream>>>(xb, rowptr2, psrc, pw, accb,
                                                        c0 * KTOT, nbc);
    dim3 g(CDIV(cm, 128), SPLIT, 1);
    gemm_tile<COUT, true><<<g, 256, 0, stream>>>(accb, W1t, msg + (size_t)c0 * COUT,
                                                 cm, KTOT * CIN);
  }
  gemm_tile<256, false><<<dim3(CDIV(N_NODES, 128), 1, 2), 256, 0, stream>>>(
      xb, rootBt, rootb, N_NODES, CIN);
  finalize_stats<<<64, 256, 0, stream>>>(msg, rootb, 256, 0, b1, rowptr2, h1, stats, N_NODES);
  bn_elu_kernel<<<CDIV(N_NODES * COUT, 256), 256, 0, stream>>>(h1, hb, stats, g1, be1, N_NODES);

  // ---- conv2 ----
  for (int c0 = 0; c0 < N_NODES; c0 += CH) {
    int cm = (N_NODES - c0 < CH) ? (N_NODES - c0) : CH;
    int nbc = cm * KTOT;
    scatter_bins<128><<<CDIV(nbc, 32), 256, 0, stream>>>(hb, rowptr2, psrc, pw, accb,
                                                         c0 * KTOT, nbc);
    dim3 g(CDIV(cm, 128), SPLIT, 1);
    gemm_tile<COUT, true><<<g, 256, 0, stream>>>(accb, W2t, msg2 + (size_t)c0 * COUT,
                                                 cm, KTOT * COUT);
  }
  gemm_tile<COUT, false><<<dim3(CDIV(N_NODES, 128), 1, 1), 256, 0, stream>>>(
      hb, Wr2t, rootb2, N_NODES, COUT);
  gemm_tile<COUT, false><<<dim3(CDIV(N_NODES, 128), 1, 1), 256, 0, stream>>>(
      xsb, Wsct, msgsc, N_NODES, CIN);
  finalize2_dual<<<64, 256, 0, stream>>>(msg2, rootb2, b2, msgsc, rootb, bsc, rowptr2,
                                         h2r, sraw, stats + 256, stats + 512, N_NODES);

  // ---- output ----
  final_out_kernel<<<CDIV(N_NODES * COUT, 256), 256, 0, stream>>>(
      h2r, sraw, stats + 256, stats + 512, g2, be2, gsc, besc, out, N_NODES);
}

// Round 6
// 855.796 us; speedup vs baseline: 5.0744x; 1.0652x over previous
//
#include <hip/hip_runtime.h>

#define N_NODES 10000
#define N_EDGES 160000
#define CIN 64
#define COUT 128
#define KTOT 125
#define NBINS (N_NODES * KTOT)          // 1,250,000
#define NPAIRS (N_EDGES * 8)            // 1,280,000
#define EPS 1e-5f

#define CDIV(a,b) (((a)+(b)-1)/(b))

typedef __attribute__((ext_vector_type(8))) short short8;
typedef __attribute__((ext_vector_type(4))) float floatx4;

static __device__ __forceinline__ unsigned short f2b(float f) {
  union { float f; unsigned u; } v; v.f = f;
  unsigned r = v.u + 0x7FFFu + ((v.u >> 16) & 1u);
  return (unsigned short)(r >> 16);
}
static __device__ __forceinline__ float b2f(unsigned short u) {
  union { unsigned u; float f; } v; v.u = ((unsigned)u) << 16;
  return v.f;
}

typedef __attribute__((address_space(1))) const unsigned int guint;
typedef __attribute__((address_space(3))) unsigned int luint;
static __device__ __forceinline__ void ld_g2l16(const void* g, void* l) {
  __builtin_amdgcn_global_load_lds((guint*)g, (luint*)l, 16, 0, 0);
}

// ---------------- (dst,k)-pair counting sort ----------------
static __device__ __forceinline__ void spline_corners(const float* __restrict__ attr, int e,
                                                      float* w8, int* k8) {
  float v0 = attr[e * 3 + 0] * 4.f;
  float v1 = attr[e * 3 + 1] * 4.f;
  float v2 = attr[e * 3 + 2] * 4.f;
  float b0 = floorf(v0), b1 = floorf(v1), b2 = floorf(v2);
  float f0 = v0 - b0, f1 = v1 - b1, f2 = v2 - b2;
  int i0 = (int)b0, i1 = (int)b1, i2 = (int)b2;
#pragma unroll
  for (int combo = 0; combo < 8; combo++) {
    int bit0 = combo & 1, bit1 = (combo >> 1) & 1, bit2 = (combo >> 2) & 1;
    w8[combo] = (bit0 ? f0 : 1.f - f0) * (bit1 ? f1 : 1.f - f1) * (bit2 ? f2 : 1.f - f2);
    int k0 = min(max(i0 + bit0, 0), 4);
    int k1 = min(max(i1 + bit1, 0), 4);
    int k2 = min(max(i2 + bit2, 0), 4);
    k8[combo] = k0 * 25 + k1 * 5 + k2;
  }
}

__global__ void pair_count(const int* __restrict__ dst, const float* __restrict__ attr,
                           int* __restrict__ cnt2, int E) {
  int e = blockIdx.x * 256 + threadIdx.x;
  if (e >= E) return;
  int d = dst[e];
  float w8[8]; int k8[8];
  spline_corners(attr, e, w8, k8);
#pragma unroll
  for (int c = 0; c < 8; c++) atomicAdd(&cnt2[d * KTOT + k8[c]], 1);
}

// cur2 pre-seeded with rowptr2 values by scan_c -> atomicAdd gives absolute slot
__global__ void pair_fill(const int* __restrict__ src, const int* __restrict__ dst,
                          const float* __restrict__ attr, int* __restrict__ cur2,
                          int* __restrict__ psrc, float* __restrict__ pw, int E) {
  int e = blockIdx.x * 256 + threadIdx.x;
  if (e >= E) return;
  int s = src[e], d = dst[e];
  float w8[8]; int k8[8];
  spline_corners(attr, e, w8, k8);
#pragma unroll
  for (int c = 0; c < 8; c++) {
    int b = d * KTOT + k8[c];
    int pos = atomicAdd(&cur2[b], 1);
    psrc[pos] = s;
    pw[pos] = w8[c];
  }
}

// ---------------- 3-kernel exclusive scan over NBINS ints ----------------
__global__ void scan_a(const int* __restrict__ in, int* __restrict__ bsum, int n) {
  __shared__ int red[256];
  int base = blockIdx.x * 2048 + threadIdx.x * 8;
  int s = 0;
#pragma unroll
  for (int j = 0; j < 8; j++) { int i = base + j; if (i < n) s += in[i]; }
  red[threadIdx.x] = s;
  __syncthreads();
  for (int st = 128; st > 0; st >>= 1) {
    if (threadIdx.x < st) red[threadIdx.x] += red[threadIdx.x + st];
    __syncthreads();
  }
  if (threadIdx.x == 0) bsum[blockIdx.x] = red[0];
}

// also zeroes the stats block (piggyback; must run before any finalize kernel)
__global__ void scan_b(const int* __restrict__ bsum, int* __restrict__ boff, int nb,
                       int* __restrict__ rowptr2, int nbins, float* __restrict__ stats) {
  for (int i = threadIdx.x; i < 6 * 128; i += 256) stats[i] = 0.f;
  __shared__ int buf[256];
  __shared__ int carry;
  if (threadIdx.x == 0) carry = 0;
  __syncthreads();
  for (int base = 0; base < nb; base += 256) {
    int i = base + threadIdx.x;
    int v = (i < nb) ? bsum[i] : 0;
    buf[threadIdx.x] = v;
    __syncthreads();
    for (int s = 1; s < 256; s <<= 1) {
      int t = (threadIdx.x >= s) ? buf[threadIdx.x - s] : 0;
      __syncthreads();
      buf[threadIdx.x] += t;
      __syncthreads();
    }
    if (i < nb) boff[i] = carry + buf[threadIdx.x] - v;
    __syncthreads();
    if (threadIdx.x == 255) carry += buf[255];
    __syncthreads();
  }
  if (threadIdx.x == 0) rowptr2[nbins] = carry;
}

// writes rowptr2[i] and seeds cur2[i] with the same value
__global__ void scan_c(const int* __restrict__ in, const int* __restrict__ boff,
                       int* __restrict__ rowptr2, int* __restrict__ cur2, int n) {
  __shared__ int buf[256];
  int base = blockIdx.x * 2048 + threadIdx.x * 8;
  int v[8], p[8];
  int s = 0;
#pragma unroll
  for (int j = 0; j < 8; j++) {
    int i = base + j;
    v[j] = (i < n) ? in[i] : 0;
    p[j] = s;
    s += v[j];
  }
  buf[threadIdx.x] = s;
  __syncthreads();
  for (int st = 1; st < 256; st <<= 1) {
    int t = (threadIdx.x >= st) ? buf[threadIdx.x - st] : 0;
    __syncthreads();
    buf[threadIdx.x] += t;
    __syncthreads();
  }
  int thr_excl = buf[threadIdx.x] - s;
  int b0 = boff[blockIdx.x];
#pragma unroll
  for (int j = 0; j < 8; j++) {
    int i = base + j;
    if (i < n) { int val = b0 + thr_excl + p[j]; rowptr2[i] = val; cur2[i] = val; }
  }
}

// ---------------- one-shot convert: xb + all weight transposes ----------------
// W1aug^T: [256, 8000] — rows 0..127 = W1^T; rows 128..255 = Wsc^T tiled over k.
// segments: xb 640000 | W1aug lo 1024000 | W2t 2048000 | rootBt(Wr1) 8192 |
//           rootBt(Wrsc) 8192 | Wr2t 16384 | W1aug hi (Wsc tiled) 1024000
__global__ void convert_all(const float* __restrict__ x, const float* __restrict__ W1,
                            const float* __restrict__ W2, const float* __restrict__ Wr1,
                            const float* __restrict__ Wrsc, const float* __restrict__ Wr2,
                            const float* __restrict__ Wsc,
                            unsigned short* __restrict__ xb, unsigned short* __restrict__ W1aug,
                            unsigned short* __restrict__ W2t, unsigned short* __restrict__ rootBt,
                            unsigned short* __restrict__ Wr2t) {
  long i = (long)blockIdx.x * 256 + threadIdx.x;
  const long n0 = 640000, n1 = n0 + 1024000, n2 = n1 + 2048000,
             n3 = n2 + 8192, n4 = n3 + 8192, n5 = n4 + 16384, n6 = n5 + 1024000;
  if (i < n0) {
    xb[i] = f2b(x[i]);
  } else if (i < n1) {
    long j = i - n0; int k = (int)(j >> 7), c = (int)(j & 127);
    W1aug[(long)c * 8000 + k] = f2b(W1[j]);
  } else if (i < n2) {
    long j = i - n1; int k = (int)(j >> 7), c = (int)(j & 127);
    W2t[(long)c * 16000 + k] = f2b(W2[j]);
  } else if (i < n3) {
    long j = i - n2; int k = (int)(j >> 7), c = (int)(j & 127);
    rootBt[c * 64 + k] = f2b(Wr1[j]);
  } else if (i < n4) {
    long j = i - n3; int k = (int)(j >> 7), c = (int)(j & 127);
    rootBt[(128 + c) * 64 + k] = f2b(Wrsc[j]);
  } else if (i < n5) {
    long j = i - n4; int k = (int)(j >> 7), c = (int)(j & 127);
    Wr2t[c * 128 + k] = f2b(Wr2[j]);
  } else if (i < n6) {
    long j = i - n5;
    int c = (int)(j / 8000), kk = (int)(j % 8000);
    W1aug[(long)(128 + c) * 8000 + kk] = f2b(Wsc[(kk & 63) * 128 + c]);
  }
}

// ---------------- scatter: one wave per 8 consecutive bins, register accumulate --
template<int C>
__global__ __launch_bounds__(256) void scatter_bins(
    const unsigned short* __restrict__ Xb, const int* __restrict__ rowptr2,
    const int* __restrict__ psrc, const float* __restrict__ pw,
    unsigned short* __restrict__ accb, int bin0, int nbins_chunk) {
  int wb0 = (blockIdx.x * 4 + (threadIdx.x >> 6)) * 8;
  if (wb0 >= nbins_chunk) return;
  int lane = threadIdx.x & 63;
  int bin = bin0 + wb0;
  int bounds = 0;
  if (lane < 9) bounds = rowptr2[bin + lane];
  int b[9];
#pragma unroll
  for (int j = 0; j < 9; j++) b[j] = __shfl(bounds, j, 64);
#pragma unroll
  for (int j = 0; j < 8; j++) {
    int wb = wb0 + j;
    if (wb >= nbins_chunk) break;
    float a0 = 0.f, a1 = 0.f;
    for (int p = b[j]; p < b[j + 1]; p++) {
      int s = psrc[p];
      float w = pw[p];
      if (C == 64) {
        a0 += w * b2f(Xb[(long)s * 64 + lane]);
      } else {
        unsigned u = *(const unsigned*)(Xb + (long)s * 128 + lane * 2);
        a0 += w * b2f((unsigned short)(u & 0xffffu));
        a1 += w * b2f((unsigned short)(u >> 16));
      }
    }
    if (C == 64) {
      accb[(long)wb * 64 + lane] = f2b(a0);
    } else {
      unsigned pk = (unsigned)f2b(a0) | ((unsigned)f2b(a1) << 16);
      *(unsigned*)(accb + (long)wb * 128 + lane * 2) = pk;
    }
  }
}

// ---------------- LDS-staged MFMA GEMM ----------------
// C[M, NCOLS] (+)= A[M,K] * Bt[NCOLS,K]^T ; 128x128 tile, col-block = blockIdx.z.
template<int NCOLS, bool ATOMIC>
__global__ __launch_bounds__(256, 2) void gemm_tile(const unsigned short* __restrict__ A,
                                                    const unsigned short* __restrict__ Bt,
                                                    float* __restrict__ C, int M, int K) {
  __shared__ unsigned short As[128 * 32];
  __shared__ unsigned short Bs[128 * 32];
  int wid = threadIdx.x >> 6, lane = threadIdx.x & 63;
  int row0 = blockIdx.x * 128;
  int cb = blockIdx.z * 128;
  int nslice = gridDim.y;
  int kslice = CDIV(K / 32, nslice) * 32;
  int kbeg = blockIdx.y * kslice;
  int kend = kbeg + kslice; if (kend > K) kend = K;
  if (kbeg >= K) return;

  int sub = lane & 3;
  int rload = lane >> 2;
  int q = lane >> 4, m16 = lane & 15;

  floatx4 acc[2][8];
#pragma unroll
  for (int t = 0; t < 2; t++)
#pragma unroll
    for (int c = 0; c < 8; c++) acc[t][c] = (floatx4){0.f, 0.f, 0.f, 0.f};

  for (int k0 = kbeg; k0 < kend; k0 += 32) {
    __syncthreads();
#pragma unroll
    for (int j = 0; j < 2; j++) {
      int tr = (wid * 2 + j) * 16 + rload;
      int gr = row0 + tr; if (gr >= M) gr = M - 1;
      ld_g2l16(A + (long)gr * K + k0 + sub * 8, As + (wid * 2 + j) * 512);
      ld_g2l16(Bt + (long)(cb + tr) * K + k0 + sub * 8, Bs + (wid * 2 + j) * 512);
    }
    __syncthreads();
#pragma unroll
    for (int t = 0; t < 2; t++) {
      int arow = wid * 32 + t * 16 + m16;
      short8 a = *(const short8*)(As + arow * 32 + q * 8);
#pragma unroll
      for (int c = 0; c < 8; c++) {
        short8 b = *(const short8*)(Bs + (c * 16 + m16) * 32 + q * 8);
        acc[t][c] = __builtin_amdgcn_mfma_f32_16x16x32_bf16(a, b, acc[t][c], 0, 0, 0);
      }
    }
  }

#pragma unroll
  for (int t = 0; t < 2; t++) {
#pragma unroll
    for (int c = 0; c < 8; c++) {
#pragma unroll
      for (int r = 0; r < 4; r++) {
        int orow = row0 + wid * 32 + t * 16 + q * 4 + r;
        if (orow < M) {
          float* p = &C[(long)orow * NCOLS + cb + c * 16 + m16];
          if (ATOMIC) atomicAdd(p, acc[t][c][r]);
          else *p = acc[t][c][r];
        }
      }
    }
  }
}

// ---------------- epilogues ----------------
// deg(n) derived from pair CSR: each edge contributes exactly 8 pairs.
static __device__ __forceinline__ float node_deg(const int* __restrict__ rowptr2, int r) {
  return (float)((rowptr2[(r + 1) * KTOT] - rowptr2[r * KTOT]) >> 3);
}

// conv1 finalize: msg in cols [0,128) of the 256-wide augmented output
__global__ void finalize_stats(const float* __restrict__ msgaug, const float* __restrict__ root,
                               const float* __restrict__ bias,
                               const int* __restrict__ rowptr2,
                               float* __restrict__ out, float* __restrict__ stats, int n) {
  int c = threadIdx.x & 127;
  float bv = bias[c];
  float s = 0.f, s2 = 0.f;
  long tot = (long)n * COUT;
  long stride = (long)gridDim.x * 256;
  for (long i = (long)blockIdx.x * 256 + threadIdx.x; i < tot; i += stride) {
    int r = (int)(i >> 7);
    float v = msgaug[(long)r * 256 + c] / fmaxf(node_deg(rowptr2, r), 1.0f)
            + root[(long)r * 256 + c] + bv;
    out[i] = v;
    s += v; s2 += v * v;
  }
  __shared__ float ls[256], ls2[256];
  ls[threadIdx.x] = s; ls2[threadIdx.x] = s2;
  __syncthreads();
  if (threadIdx.x < 128) {
    atomicAdd(&stats[c], ls[threadIdx.x] + ls[threadIdx.x + 128]);
    atomicAdd(&stats[128 + c], ls2[threadIdx.x] + ls2[threadIdx.x + 128]);
  }
}

// fused finalize for conv2 (mean) + shortcut (mean, from augmented conv1 cols 128..255)
__global__ void finalize2_dual(const float* __restrict__ msg2, const float* __restrict__ rootb2,
                               const float* __restrict__ b2, const float* __restrict__ msgaug,
                               const float* __restrict__ rootb, const float* __restrict__ bsc,
                               const int* __restrict__ rowptr2, float* __restrict__ h2r,
                               float* __restrict__ sraw, float* __restrict__ stats2,
                               float* __restrict__ statssc, int n) {
  int c = threadIdx.x & 127;
  float bv2 = b2[c], bvsc = bsc[c];
  float sa = 0.f, sb = 0.f, ta = 0.f, tb = 0.f;
  long tot = (long)n * COUT;
  long stride = (long)gridDim.x * 256;
  for (long i = (long)blockIdx.x * 256 + threadIdx.x; i < tot; i += stride) {
    int r = (int)(i >> 7);
    float invdeg = 1.0f / fmaxf(node_deg(rowptr2, r), 1.0f);
    float v2 = msg2[i] * invdeg + rootb2[i] + bv2;
    h2r[i] = v2;
    sa += v2; sb += v2 * v2;
    float vs = msgaug[(long)r * 256 + 128 + c] * invdeg
             + rootb[(long)r * 256 + 128 + c] + bvsc;
    sraw[i] = vs;
    ta += vs; tb += vs * vs;
  }
  __shared__ float l0[256], l1[256], l2[256], l3[256];
  l0[threadIdx.x] = sa; l1[threadIdx.x] = sb; l2[threadIdx.x] = ta; l3[threadIdx.x] = tb;
  __syncthreads();
  if (threadIdx.x < 128) {
    atomicAdd(&stats2[c], l0[threadIdx.x] + l0[threadIdx.x + 128]);
    atomicAdd(&stats2[128 + c], l1[threadIdx.x] + l1[threadIdx.x + 128]);
    atomicAdd(&statssc[c], l2[threadIdx.x] + l2[threadIdx.x + 128]);
    atomicAdd(&statssc[128 + c], l3[threadIdx.x] + l3[threadIdx.x + 128]);
  }
}

__global__ void bn_elu_kernel(float* __restrict__ h, unsigned short* __restrict__ hb,
                              const float* __restrict__ stats, const float* __restrict__ g,
                              const float* __restrict__ be, int n) {
  long i = (long)blockIdx.x * 256 + threadIdx.x;
  if (i >= (long)n * COUT) return;
  int c = (int)(i & 127);
  float inv_n = 1.0f / n;
  float mu = stats[c] * inv_n;
  float var = stats[128 + c] * inv_n - mu * mu;
  float v = (h[i] - mu) * rsqrtf(var + EPS) * g[c] + be[c];
  v = v > 0.f ? v : expm1f(v);
  h[i] = v;
  hb[i] = f2b(v);
}

__global__ void final_out_kernel(const float* __restrict__ h2, const float* __restrict__ sraw,
                                 const float* __restrict__ st2, const float* __restrict__ stsc,
                                 const float* __restrict__ g2, const float* __restrict__ be2,
                                 const float* __restrict__ gsc, const float* __restrict__ besc,
                                 float* __restrict__ out, int n) {
  long i = (long)blockIdx.x * 256 + threadIdx.x;
  if (i >= (long)n * COUT) return;
  int c = (int)(i & 127);
  float inv_n = 1.0f / n;
  float mu2 = st2[c] * inv_n;
  float var2 = st2[128 + c] * inv_n - mu2 * mu2;
  float a = (h2[i] - mu2) * rsqrtf(var2 + EPS) * g2[c] + be2[c];
  float musc = stsc[c] * inv_n;
  float varsc = stsc[128 + c] * inv_n - musc * musc;
  float b = (sraw[i] - musc) * rsqrtf(varsc + EPS) * gsc[c] + besc[c];
  float v = a + b;
  out[i] = v > 0.f ? v : expm1f(v);
}

// ---------------- host ----------------
extern "C" void kernel_launch(void* const* d_in, const int* in_sizes, int n_in,
                              void* d_out, int out_size, void* d_ws, size_t ws_size,
                              hipStream_t stream) {
  const float* x    = (const float*)d_in[0];
  const int*   eidx = (const int*)d_in[1];
  const float* attr = (const float*)d_in[2];
  const float* W1   = (const float*)d_in[3];
  const float* Wr1  = (const float*)d_in[4];
  const float* b1   = (const float*)d_in[5];
  const float* g1   = (const float*)d_in[6];
  const float* be1  = (const float*)d_in[7];
  const float* W2   = (const float*)d_in[8];
  const float* Wr2  = (const float*)d_in[9];
  const float* b2   = (const float*)d_in[10];
  const float* g2   = (const float*)d_in[11];
  const float* be2  = (const float*)d_in[12];
  const float* Wsc  = (const float*)d_in[13];
  const float* Wrsc = (const float*)d_in[14];
  const float* bsc  = (const float*)d_in[15];
  const float* gsc  = (const float*)d_in[16];
  const float* besc = (const float*)d_in[17];
  float* out = (float*)d_out;

  const int* src = eidx;
  const int* dst = eidx + N_EDGES;

  char* base = (char*)d_ws;
  size_t off = 0;
  auto alloc = [&](size_t bytes) -> char* {
    char* p = base + off;
    off += (bytes + 255) & ~(size_t)255;
    return p;
  };
  int* cnt2   = (int*)alloc((size_t)NBINS * 4);
  int* cur2   = (int*)alloc((size_t)NBINS * 4);
  int* rowptr2= (int*)alloc((size_t)(NBINS + 1) * 4);
  const int NB_SCAN = CDIV(NBINS, 2048);
  int* bsum   = (int*)alloc((size_t)(NB_SCAN + 1) * 4);
  int* boff   = (int*)alloc((size_t)(NB_SCAN + 1) * 4);
  int* psrc   = (int*)alloc((size_t)NPAIRS * 4);
  float* pw   = (float*)alloc((size_t)NPAIRS * 4);
  unsigned short* xb    = (unsigned short*)alloc((size_t)N_NODES * CIN * 2);
  unsigned short* hb    = (unsigned short*)alloc((size_t)N_NODES * COUT * 2);
  unsigned short* W1aug = (unsigned short*)alloc((size_t)256 * KTOT * CIN * 2);
  unsigned short* W2t   = (unsigned short*)alloc((size_t)COUT * KTOT * COUT * 2);
  unsigned short* rootBt= (unsigned short*)alloc((size_t)256 * CIN * 2);
  unsigned short* Wr2t  = (unsigned short*)alloc((size_t)COUT * COUT * 2);
  float* msgaug= (float*)alloc((size_t)N_NODES * 256 * 4);    // conv1+shortcut (zeroed)
  float* msg2  = (float*)alloc((size_t)N_NODES * COUT * 4);   // conv2 (zeroed, adjacent)
  float* rootb = (float*)alloc((size_t)N_NODES * 256 * 4);    // [Wr1 | Wrsc] outputs
  float* rootb2= (float*)alloc((size_t)N_NODES * COUT * 4);
  float* h1    = (float*)alloc((size_t)N_NODES * COUT * 4);
  float* h2r   = (float*)alloc((size_t)N_NODES * COUT * 4);
  float* sraw  = (float*)alloc((size_t)N_NODES * COUT * 4);
  float* stats = (float*)alloc(6 * 128 * 4);
  unsigned short* accb = (unsigned short*)(base + off);
  size_t avail = (ws_size > off) ? (ws_size - off) : 0;
  size_t per_node = (size_t)KTOT * COUT * 2;
  size_t chmax = avail / per_node;
  int CH = (int)((chmax < (size_t)N_NODES) ? chmax : (size_t)N_NODES);
  if (CH < 1) CH = 1;
  const int SPLIT = 10;

  hipMemsetAsync(cnt2, 0, (size_t)NBINS * 4, stream);
  hipMemsetAsync(msgaug, 0, (size_t)N_NODES * (256 + 128) * 4, stream); // msgaug + msg2

  // (dst,k)-pair counting sort (stats zeroed in scan_b, cur2 seeded in scan_c)
  pair_count<<<CDIV(N_EDGES, 256), 256, 0, stream>>>(dst, attr, cnt2, N_EDGES);
  scan_a<<<NB_SCAN, 256, 0, stream>>>(cnt2, bsum, NBINS);
  scan_b<<<1, 256, 0, stream>>>(bsum, boff, NB_SCAN, rowptr2, NBINS, stats);
  scan_c<<<NB_SCAN, 256, 0, stream>>>(cnt2, boff, rowptr2, cur2, NBINS);
  pair_fill<<<CDIV(N_EDGES, 256), 256, 0, stream>>>(src, dst, attr, cur2, psrc, pw, N_EDGES);

  const long CONV_TOT = 640000L + 1024000L + 2048000L + 8192 + 8192 + 16384 + 1024000L;
  convert_all<<<CDIV(CONV_TOT, 256), 256, 0, stream>>>(x, W1, W2, Wr1, Wrsc, Wr2, Wsc,
                                                       xb, W1aug, W2t, rootBt, Wr2t);

  // ---- conv1 (+ shortcut spline via augmented cols 128..255) ----
  for (int c0 = 0; c0 < N_NODES; c0 += CH) {
    int cm = (N_NODES - c0 < CH) ? (N_NODES - c0) : CH;
    int nbc = cm * KTOT;
    scatter_bins<64><<<CDIV(nbc, 32), 256, 0, stream>>>(xb, rowptr2, psrc, pw, accb,
                                                        c0 * KTOT, nbc);
    dim3 g(CDIV(cm, 128), SPLIT, 2);
    gemm_tile<256, true><<<g, 256, 0, stream>>>(accb, W1aug, msgaug + (size_t)c0 * 256,
                                                cm, KTOT * CIN);
  }
  gemm_tile<256, false><<<dim3(CDIV(N_NODES, 128), 1, 2), 256, 0, stream>>>(
      xb, rootBt, rootb, N_NODES, CIN);
  finalize_stats<<<64, 256, 0, stream>>>(msgaug, rootb, b1, rowptr2, h1, stats, N_NODES);
  bn_elu_kernel<<<CDIV(N_NODES * COUT, 256), 256, 0, stream>>>(h1, hb, stats, g1, be1, N_NODES);

  // ---- conv2 ----
  for (int c0 = 0; c0 < N_NODES; c0 += CH) {
    int cm = (N_NODES - c0 < CH) ? (N_NODES - c0) : CH;
    int nbc = cm * KTOT;
    scatter_bins<128><<<CDIV(nbc, 32), 256, 0, stream>>>(hb, rowptr2, psrc, pw, accb,
                                                         c0 * KTOT, nbc);
    dim3 g(CDIV(cm, 128), SPLIT, 1);
    gemm_tile<COUT, true><<<g, 256, 0, stream>>>(accb, W2t, msg2 + (size_t)c0 * COUT,
                                                 cm, KTOT * COUT);
  }
  gemm_tile<COUT, false><<<dim3(CDIV(N_NODES, 128), 1, 1), 256, 0, stream>>>(
      hb, Wr2t, rootb2, N_NODES, COUT);
  finalize2_dual<<<64, 256, 0, stream>>>(msg2, rootb2, b2, msgaug, rootb, bsc, rowptr2,
                                         h2r, sraw, stats + 256, stats + 512, N_NODES);

  // ---- output ----
  final_out_kernel<<<CDIV(N_NODES * COUT, 256), 256, 0, stream>>>(
      h2r, sraw, stats + 256, stats + 512, g2, be2, gsc, besc, out, N_NODES);
}